// Round 4
// baseline (785.945 us; speedup 1.0000x reference)
//
#include <hip/hip_runtime.h>
#include <hip/hip_bf16.h>
#include <cstdint>
#include <cstddef>

#define GAT_H 8
#define DEGBINS 1024

// ======================= CSR build (once per call) =======================

__global__ void hist_kernel(const int* __restrict__ ei, int* __restrict__ deg,
                            int nE, int nN) {
    const int e = blockIdx.x * blockDim.x + threadIdx.x;
    if (e >= nE + nN) return;
    const int dst = (e < nE) ? ei[nE + e] : (e - nE);   // self-loop tail
    atomicAdd(&deg[dst], 1);
}

// single-workgroup exclusive scan: rowptr[0]=0, rowptr[i+1]=sum(deg[0..i])
__global__ __launch_bounds__(1024) void scan_kernel(const int* __restrict__ deg,
                                                    int* __restrict__ rowptr, int N) {
    __shared__ int wsum[16];
    __shared__ int carry;
    const int tid = threadIdx.x;
    const int lane = tid & 63, wid = tid >> 6;
    if (tid == 0) carry = 0;
    __syncthreads();
    for (int base = 0; base < N; base += 1024) {
        const int i = base + tid;
        int incl = (i < N) ? deg[i] : 0;
        #pragma unroll
        for (int d = 1; d < 64; d <<= 1) {
            const int t = __shfl_up(incl, d, 64);
            if (lane >= d) incl += t;
        }
        if (lane == 63) wsum[wid] = incl;
        __syncthreads();
        if (tid == 0) {
            int run = carry;
            #pragma unroll
            for (int w = 0; w < 16; ++w) { const int t2 = wsum[w]; wsum[w] = run; run += t2; }
            carry = run;
        }
        __syncthreads();
        if (i < N) rowptr[i + 1] = wsum[wid] + incl;
        __syncthreads();   // protect wsum before next iteration
    }
    if (tid == 0) rowptr[0] = 0;
}

__global__ void copy_int_kernel(const int* __restrict__ a, int* __restrict__ b, int n) {
    const int i = blockIdx.x * blockDim.x + threadIdx.x;
    if (i < n) b[i] = a[i];
}

__global__ void scatter_kernel(const int* __restrict__ ei, int* __restrict__ woff,
                               int* __restrict__ esrc, int nE, int nN) {
    const int e = blockIdx.x * blockDim.x + threadIdx.x;
    if (e >= nE + nN) return;
    int src, dst;
    if (e < nE) { src = ei[e]; dst = ei[nE + e]; }
    else        { src = dst = e - nE; }
    const int pos = atomicAdd(&woff[dst], 1);
    esrc[pos] = src;
}

// ======================= degree-sorted dst order (counting sort) =======================

__global__ void deghist_kernel(const int* __restrict__ deg, int* __restrict__ hist, int N) {
    __shared__ int lh[DEGBINS];
    for (int i = threadIdx.x; i < DEGBINS; i += blockDim.x) lh[i] = 0;
    __syncthreads();
    const int t = blockIdx.x * blockDim.x + threadIdx.x;
    if (t < N) atomicAdd(&lh[min(deg[t], DEGBINS - 1)], 1);
    __syncthreads();
    for (int i = threadIdx.x; i < DEGBINS; i += blockDim.x)
        if (lh[i]) atomicAdd(&hist[i], lh[i]);
}

__global__ __launch_bounds__(DEGBINS) void scanbins_kernel(const int* __restrict__ hist,
                                                           int* __restrict__ bins) {
    __shared__ int tmp[DEGBINS];
    const int t = threadIdx.x;
    const int v = hist[t];
    tmp[t] = v;
    __syncthreads();
    for (int d = 1; d < DEGBINS; d <<= 1) {
        const int add = (t >= d) ? tmp[t - d] : 0;
        __syncthreads();
        tmp[t] += add;
        __syncthreads();
    }
    bins[t] = tmp[t] - v;   // exclusive
}

__global__ void ordscatter_kernel(const int* __restrict__ deg, int* __restrict__ bins,
                                  int* __restrict__ order, int N) {
    const int t = blockIdx.x * blockDim.x + threadIdx.x;
    if (t >= N) return;
    const int pos = atomicAdd(&bins[min(deg[t], DEGBINS - 1)], 1);
    order[pos] = t;
}

// ======================= node matmul (register-blocked, LDS-staged) =======================

template<int D, int C, int KK>
__global__ __launch_bounds__(256) void matmul_tile(const float* __restrict__ X,
                                                   const float* __restrict__ W,
                                                   float* __restrict__ Hout, int N) {
    constexpr int CG  = C / 8;
    constexpr int NGR = 256 / CG;
    constexpr int NPT = 64 / NGR;
    constexpr int XS  = KK + 4;
    __shared__ float xs[64][XS];
    __shared__ float wsh[KK][C];

    const int n0 = blockIdx.x * 64;
    const int tid = threadIdx.x;
    const int cg = tid % CG, ngr = tid / CG;
    const int c0 = cg * 8;

    float acc[NPT][8];
    #pragma unroll
    for (int i = 0; i < NPT; ++i)
        #pragma unroll
        for (int j = 0; j < 8; ++j) acc[i][j] = 0.f;

    for (int k0 = 0; k0 < D; k0 += KK) {
        for (int t = tid; t < 64 * (KK / 4); t += 256) {
            const int row = t / (KK / 4), c4 = (t % (KK / 4)) * 4;
            const int n = n0 + row;
            float4 v = make_float4(0.f, 0.f, 0.f, 0.f);
            if (n < N) v = *reinterpret_cast<const float4*>(&X[(size_t)n * D + k0 + c4]);
            *reinterpret_cast<float4*>(&xs[row][c4]) = v;
        }
        for (int t = tid; t < KK * (C / 4); t += 256) {
            const int row = t / (C / 4), c4 = (t % (C / 4)) * 4;
            *reinterpret_cast<float4*>(&wsh[row][c4]) =
                *reinterpret_cast<const float4*>(&W[(size_t)(k0 + row) * C + c4]);
        }
        __syncthreads();

        #pragma unroll
        for (int k4 = 0; k4 < KK; k4 += 4) {
            float4 xv[NPT];
            #pragma unroll
            for (int i = 0; i < NPT; ++i)
                xv[i] = *reinterpret_cast<const float4*>(&xs[ngr * NPT + i][k4]);
            #pragma unroll
            for (int kk = 0; kk < 4; ++kk) {
                const float4 w0 = *reinterpret_cast<const float4*>(&wsh[k4 + kk][c0]);
                const float4 w1 = *reinterpret_cast<const float4*>(&wsh[k4 + kk][c0 + 4]);
                #pragma unroll
                for (int i = 0; i < NPT; ++i) {
                    const float xk = (kk == 0) ? xv[i].x : (kk == 1) ? xv[i].y
                                   : (kk == 2) ? xv[i].z : xv[i].w;
                    acc[i][0] += xk * w0.x; acc[i][1] += xk * w0.y;
                    acc[i][2] += xk * w0.z; acc[i][3] += xk * w0.w;
                    acc[i][4] += xk * w1.x; acc[i][5] += xk * w1.y;
                    acc[i][6] += xk * w1.z; acc[i][7] += xk * w1.w;
                }
            }
        }
        __syncthreads();
    }

    #pragma unroll
    for (int i = 0; i < NPT; ++i) {
        const int n = n0 + ngr * NPT + i;
        if (n < N) {
            float4 o0 = make_float4(acc[i][0], acc[i][1], acc[i][2], acc[i][3]);
            float4 o1 = make_float4(acc[i][4], acc[i][5], acc[i][6], acc[i][7]);
            *reinterpret_cast<float4*>(&Hout[(size_t)n * C + c0])     = o0;
            *reinterpret_cast<float4*>(&Hout[(size_t)n * C + c0 + 4]) = o1;
        }
    }
}

// ======================= attention logits per (node, head) =======================

__global__ void attnlogit_kernel(const float* __restrict__ Hf,
                                 const float* __restrict__ a_src,
                                 const float* __restrict__ a_dst,
                                 float* __restrict__ als, float* __restrict__ ald,
                                 int N, int F) {
    const int t = blockIdx.x * blockDim.x + threadIdx.x;
    if (t >= N * GAT_H) return;
    const int n = t / GAT_H, h = t % GAT_H;
    const float* hp = Hf + ((size_t)n * GAT_H + h) * F;
    float s1 = 0.f, s2 = 0.f;
    for (int f = 0; f < F; ++f) {
        const float v = hp[f];
        s1 += v * a_src[h * F + f];
        s2 += v * a_dst[h * F + f];
    }
    als[t] = s1; ald[t] = s2;
}

// ======================= pass 1: segment max of logits =======================

__global__ void gat_max(const int* __restrict__ rowptr, const int* __restrict__ esrc,
                        const int* __restrict__ order,
                        const float* __restrict__ als, const float* __restrict__ ald,
                        float* __restrict__ m, int N) {
    const int t = blockIdx.x * blockDim.x + threadIdx.x;
    if (t >= N * GAT_H) return;
    const int dst = order[t >> 3], h = t & 7;
    const int beg = rowptr[dst], end = rowptr[dst + 1];
    const float adh = ald[dst * GAT_H + h];
    float mm = -1e30f;
    for (int i = beg; i < end; ++i) {
        float x = als[esrc[i] * GAT_H + h] + adh;
        x = x > 0.f ? x : 0.2f * x;
        mm = fmaxf(mm, x);
    }
    m[dst * GAT_H + h] = mm;
}

// ======================= pass 2: branch-free weighted sum + ELU =======================

template<int F>
__global__ void gat_pass2(const int* __restrict__ rowptr, const int* __restrict__ esrc,
                          const int* __restrict__ order,
                          const float* __restrict__ als, const float* __restrict__ ald,
                          const float* __restrict__ m,
                          const float* __restrict__ Hf, const float* __restrict__ b,
                          float* __restrict__ out, int N) {
    const int t = blockIdx.x * blockDim.x + threadIdx.x;
    if (t >= N * GAT_H) return;
    const int dst = order[t >> 3], h = t & 7;
    const int beg = rowptr[dst], end = rowptr[dst + 1];
    const float adh = ald[dst * GAT_H + h];
    const float mm  = m[dst * GAT_H + h];
    float s = 0.f;
    float4 acc[F / 4];
    #pragma unroll
    for (int j = 0; j < F / 4; ++j) acc[j] = make_float4(0.f, 0.f, 0.f, 0.f);

    // software pipeline: next src index + its logit prefetched one iteration ahead
    int src = esrc[beg];                       // deg >= 1 (self-loop)
    float al = als[src * GAT_H + h];
    for (int i = beg; i < end; ++i) {
        const float4* hp = reinterpret_cast<const float4*>(Hf + ((size_t)src * GAT_H + h) * F);
        float4 v[F / 4];
        #pragma unroll
        for (int j = 0; j < F / 4; ++j) v[j] = hp[j];

        const int inext = (i + 1 < end) ? i + 1 : i;
        const int nsrc = esrc[inext];
        const float nal = als[nsrc * GAT_H + h];

        float x = al + adh;
        x = x > 0.f ? x : 0.2f * x;
        const float p = __expf(x - mm);
        s += p;
        #pragma unroll
        for (int j = 0; j < F / 4; ++j) {
            acc[j].x += p * v[j].x; acc[j].y += p * v[j].y;
            acc[j].z += p * v[j].z; acc[j].w += p * v[j].w;
        }
        src = nsrc; al = nal;
    }

    const float inv = 1.f / (s + 1e-16f);
    #pragma unroll
    for (int j = 0; j < F / 4; ++j) {
        const float o[4] = {acc[j].x, acc[j].y, acc[j].z, acc[j].w};
        #pragma unroll
        for (int q = 0; q < 4; ++q) {
            const float val = o[q] * inv + b[h * F + 4 * j + q];
            out[((size_t)dst * GAT_H + h) * F + 4 * j + q] =
                val > 0.f ? val : expm1f(val);   // ELU
        }
    }
}

// ======================= pooling (sorted batch -> binary search) + MLP, fused =======================

__global__ __launch_bounds__(256) void pool_mlp_kernel(
        const float* __restrict__ A, const int* __restrict__ batch,
        const float* __restrict__ fc1w, const float* __restrict__ fc1b,
        const float* __restrict__ fc2w, const float* __restrict__ fc2b,
        float* __restrict__ out, int N) {
    const int g = blockIdx.x;
    int lo, hi;
    {
        int l = 0, h2 = N;
        while (l < h2) { const int mid = (l + h2) >> 1; if (batch[mid] < g) l = mid + 1; else h2 = mid; }
        lo = l;
        h2 = N;
        while (l < h2) { const int mid = (l + h2) >> 1; if (batch[mid] < g + 1) l = mid + 1; else h2 = mid; }
        hi = l;
    }
    __shared__ float part[256];
    __shared__ float pl[128];
    __shared__ float red2[32];
    const int tid = threadIdx.x;
    const int c = tid & 127, half = tid >> 7;
    float acc = 0.f;
    for (int n = lo + half; n < hi; n += 2) acc += A[(size_t)n * 128 + c];
    part[tid] = acc;
    __syncthreads();
    if (tid < 128) {
        const float tot = part[tid] + part[tid + 128];
        const float cntf = (float)(hi - lo);
        pl[tid] = tot / fmaxf(cntf, 1.f);
    }
    __syncthreads();
    if (tid < 32) {
        float a = fc1b[tid];
        for (int k = 0; k < 128; ++k) a += pl[k] * fc1w[k * 32 + tid];
        a = fmaxf(a, 0.f);
        red2[tid] = a * fc2w[tid];
    }
    __syncthreads();
    if (tid == 0) {
        float sum = fc2b[0];
        for (int k = 0; k < 32; ++k) sum += red2[k];
        out[g] = sum;
    }
}

// ======================= launch =======================

extern "C" void kernel_launch(void* const* d_in, const int* in_sizes, int n_in,
                              void* d_out, int out_size, void* d_ws, size_t ws_size,
                              hipStream_t stream) {
    const float* x     = (const float*)d_in[0];
    const int*   ei    = (const int*)  d_in[1];
    const int*   batch = (const int*)  d_in[2];
    const float* W1 = (const float*)d_in[3],  *as1 = (const float*)d_in[4],
               *ad1 = (const float*)d_in[5],  *b1  = (const float*)d_in[6];
    const float* W2 = (const float*)d_in[7],  *as2 = (const float*)d_in[8],
               *ad2 = (const float*)d_in[9],  *b2  = (const float*)d_in[10];
    const float* W3 = (const float*)d_in[11], *as3 = (const float*)d_in[12],
               *ad3 = (const float*)d_in[13], *b3  = (const float*)d_in[14];
    const float* fc1w = (const float*)d_in[15], *fc1b = (const float*)d_in[16];
    const float* fc2w = (const float*)d_in[17], *fc2b = (const float*)d_in[18];

    const int N  = in_sizes[0] / 16;     // 50000
    const int NE = in_sizes[1] / 2;      // 800000
    const int NG = out_size;             // 256
    const int ET = NE + N;               // edges incl. self-loops

    // workspace layout (4-byte elements)
    float* ws = (float*)d_ws;
    size_t off = 0;
    float* A    = ws + off; off += (size_t)N * 128;
    float* B    = ws + off; off += (size_t)N * 128;
    float* als  = ws + off; off += (size_t)N * GAT_H;
    float* ald  = ws + off; off += (size_t)N * GAT_H;
    float* m    = ws + off; off += (size_t)N * GAT_H;
    int* deg    = (int*)(ws + off); off += N;
    int* rowptr = (int*)(ws + off); off += N + 1;
    int* woff   = (int*)(ws + off); off += N;
    int* esrc   = (int*)(ws + off); off += ET;
    int* dhist  = (int*)(ws + off); off += DEGBINS;
    int* dbins  = (int*)(ws + off); off += DEGBINS;
    int* order  = (int*)(ws + off); off += N;

    // ---- CSR build + degree-sorted order (graph identical for all 3 layers) ----
    hipMemsetAsync(deg, 0, (size_t)N * sizeof(int), stream);
    hipMemsetAsync(dhist, 0, DEGBINS * sizeof(int), stream);
    hist_kernel<<<(ET + 255) / 256, 256, 0, stream>>>(ei, deg, NE, N);
    scan_kernel<<<1, 1024, 0, stream>>>(deg, rowptr, N);
    copy_int_kernel<<<(N + 255) / 256, 256, 0, stream>>>(rowptr, woff, N);
    scatter_kernel<<<(ET + 255) / 256, 256, 0, stream>>>(ei, woff, esrc, NE, N);
    deghist_kernel<<<(N + 255) / 256, 256, 0, stream>>>(deg, dhist, N);
    scanbins_kernel<<<1, DEGBINS, 0, stream>>>(dhist, dbins);
    ordscatter_kernel<<<(N + 255) / 256, 256, 0, stream>>>(deg, dbins, order, N);

    const int NH = N * GAT_H;
    const int NHB = (NH + 255) / 256;
    const int NB = (N + 63) / 64;

    // ---- layer 1: 16 -> 8x8 ----
    matmul_tile<16, 64, 16><<<NB, 256, 0, stream>>>(x, W1, B, N);
    attnlogit_kernel<<<NHB, 256, 0, stream>>>(B, as1, ad1, als, ald, N, 8);
    gat_max<<<NHB, 256, 0, stream>>>(rowptr, esrc, order, als, ald, m, N);
    gat_pass2<8><<<NHB, 256, 0, stream>>>(rowptr, esrc, order, als, ald, m, B, b1, A, N);

    // ---- layer 2: 64 -> 8x16 ----
    matmul_tile<64, 128, 32><<<NB, 256, 0, stream>>>(A, W2, B, N);
    attnlogit_kernel<<<NHB, 256, 0, stream>>>(B, as2, ad2, als, ald, N, 16);
    gat_max<<<NHB, 256, 0, stream>>>(rowptr, esrc, order, als, ald, m, N);
    gat_pass2<16><<<NHB, 256, 0, stream>>>(rowptr, esrc, order, als, ald, m, B, b2, A, N);

    // ---- layer 3: 128 -> 8x16 ----
    matmul_tile<128, 128, 32><<<NB, 256, 0, stream>>>(A, W3, B, N);
    attnlogit_kernel<<<NHB, 256, 0, stream>>>(B, as3, ad3, als, ald, N, 16);
    gat_max<<<NHB, 256, 0, stream>>>(rowptr, esrc, order, als, ald, m, N);
    gat_pass2<16><<<NHB, 256, 0, stream>>>(rowptr, esrc, order, als, ald, m, B, b3, A, N);

    // ---- pool + MLP ----
    pool_mlp_kernel<<<NG, 256, 0, stream>>>(A, batch, fc1w, fc1b, fc2w, fc2b,
                                            (float*)d_out, N);
}

// Round 5
// 626.164 us; speedup vs baseline: 1.2552x; 1.2552x over previous
//
#include <hip/hip_runtime.h>
#include <hip/hip_bf16.h>
#include <cstdint>
#include <cstddef>

#define GAT_H 8

// ======================= CSR build (once per call) =======================

__global__ void hist_kernel(const int* __restrict__ ei, int* __restrict__ deg,
                            int nE, int nN) {
    const int e = blockIdx.x * blockDim.x + threadIdx.x;
    if (e >= nE + nN) return;
    const int dst = (e < nE) ? ei[nE + e] : (e - nE);   // self-loop tail
    atomicAdd(&deg[dst], 1);
}

// single-workgroup exclusive scan: rowptr[0]=0, rowptr[i+1]=sum(deg[0..i])
__global__ __launch_bounds__(1024) void scan_kernel(const int* __restrict__ deg,
                                                    int* __restrict__ rowptr, int N) {
    __shared__ int wsum[16];
    __shared__ int carry;
    const int tid = threadIdx.x;
    const int lane = tid & 63, wid = tid >> 6;
    if (tid == 0) carry = 0;
    __syncthreads();
    for (int base = 0; base < N; base += 1024) {
        const int i = base + tid;
        int incl = (i < N) ? deg[i] : 0;
        #pragma unroll
        for (int d = 1; d < 64; d <<= 1) {
            const int t = __shfl_up(incl, d, 64);
            if (lane >= d) incl += t;
        }
        if (lane == 63) wsum[wid] = incl;
        __syncthreads();
        if (tid == 0) {
            int run = carry;
            #pragma unroll
            for (int w = 0; w < 16; ++w) { const int t2 = wsum[w]; wsum[w] = run; run += t2; }
            carry = run;
        }
        __syncthreads();
        if (i < N) rowptr[i + 1] = wsum[wid] + incl;
        __syncthreads();   // protect wsum before next iteration
    }
    if (tid == 0) rowptr[0] = 0;
}

__global__ void copy_int_kernel(const int* __restrict__ a, int* __restrict__ b, int n) {
    const int i = blockIdx.x * blockDim.x + threadIdx.x;
    if (i < n) b[i] = a[i];
}

__global__ void scatter_kernel(const int* __restrict__ ei, int* __restrict__ woff,
                               int* __restrict__ esrc, int nE, int nN) {
    const int e = blockIdx.x * blockDim.x + threadIdx.x;
    if (e >= nE + nN) return;
    int src, dst;
    if (e < nE) { src = ei[e]; dst = ei[nE + e]; }
    else        { src = dst = e - nE; }
    const int pos = atomicAdd(&woff[dst], 1);
    esrc[pos] = src;
}

// ======================= node matmul (register-blocked, LDS-staged) =======================

template<int D, int C, int KK>
__global__ __launch_bounds__(256) void matmul_tile(const float* __restrict__ X,
                                                   const float* __restrict__ W,
                                                   float* __restrict__ Hout, int N) {
    constexpr int CG  = C / 8;
    constexpr int NGR = 256 / CG;
    constexpr int NPT = 64 / NGR;
    constexpr int XS  = KK + 4;
    __shared__ float xs[64][XS];
    __shared__ float wsh[KK][C];

    const int n0 = blockIdx.x * 64;
    const int tid = threadIdx.x;
    const int cg = tid % CG, ngr = tid / CG;
    const int c0 = cg * 8;

    float acc[NPT][8];
    #pragma unroll
    for (int i = 0; i < NPT; ++i)
        #pragma unroll
        for (int j = 0; j < 8; ++j) acc[i][j] = 0.f;

    for (int k0 = 0; k0 < D; k0 += KK) {
        for (int t = tid; t < 64 * (KK / 4); t += 256) {
            const int row = t / (KK / 4), c4 = (t % (KK / 4)) * 4;
            const int n = n0 + row;
            float4 v = make_float4(0.f, 0.f, 0.f, 0.f);
            if (n < N) v = *reinterpret_cast<const float4*>(&X[(size_t)n * D + k0 + c4]);
            *reinterpret_cast<float4*>(&xs[row][c4]) = v;
        }
        for (int t = tid; t < KK * (C / 4); t += 256) {
            const int row = t / (C / 4), c4 = (t % (C / 4)) * 4;
            *reinterpret_cast<float4*>(&wsh[row][c4]) =
                *reinterpret_cast<const float4*>(&W[(size_t)(k0 + row) * C + c4]);
        }
        __syncthreads();

        #pragma unroll
        for (int k4 = 0; k4 < KK; k4 += 4) {
            float4 xv[NPT];
            #pragma unroll
            for (int i = 0; i < NPT; ++i)
                xv[i] = *reinterpret_cast<const float4*>(&xs[ngr * NPT + i][k4]);
            #pragma unroll
            for (int kk = 0; kk < 4; ++kk) {
                const float4 w0 = *reinterpret_cast<const float4*>(&wsh[k4 + kk][c0]);
                const float4 w1 = *reinterpret_cast<const float4*>(&wsh[k4 + kk][c0 + 4]);
                #pragma unroll
                for (int i = 0; i < NPT; ++i) {
                    const float xk = (kk == 0) ? xv[i].x : (kk == 1) ? xv[i].y
                                   : (kk == 2) ? xv[i].z : xv[i].w;
                    acc[i][0] += xk * w0.x; acc[i][1] += xk * w0.y;
                    acc[i][2] += xk * w0.z; acc[i][3] += xk * w0.w;
                    acc[i][4] += xk * w1.x; acc[i][5] += xk * w1.y;
                    acc[i][6] += xk * w1.z; acc[i][7] += xk * w1.w;
                }
            }
        }
        __syncthreads();
    }

    #pragma unroll
    for (int i = 0; i < NPT; ++i) {
        const int n = n0 + ngr * NPT + i;
        if (n < N) {
            float4 o0 = make_float4(acc[i][0], acc[i][1], acc[i][2], acc[i][3]);
            float4 o1 = make_float4(acc[i][4], acc[i][5], acc[i][6], acc[i][7]);
            *reinterpret_cast<float4*>(&Hout[(size_t)n * C + c0])     = o0;
            *reinterpret_cast<float4*>(&Hout[(size_t)n * C + c0 + 4]) = o1;
        }
    }
}

// ======================= attention logits + global per-head max of als =======================
// Mh[h] must be 0-initialized; after this kernel Mh[h] = max(0, max_n als[n,h]).
// (Any per-(dst,h) value >= segment max gives an identical softmax - shift invariance.)

__global__ void attnlogit_kernel(const float* __restrict__ Hf,
                                 const float* __restrict__ a_src,
                                 const float* __restrict__ a_dst,
                                 float* __restrict__ als, float* __restrict__ ald,
                                 float* __restrict__ Mh, int N, int F) {
    __shared__ float sh[256];
    const int t = blockIdx.x * blockDim.x + threadIdx.x;
    const int tid = threadIdx.x;
    float s1 = -1e30f;
    if (t < N * GAT_H) {
        const int n = t / GAT_H, h = t % GAT_H;
        const float* hp = Hf + ((size_t)n * GAT_H + h) * F;
        float a1 = 0.f, a2 = 0.f;
        for (int f = 0; f < F; ++f) {
            const float v = hp[f];
            a1 += v * a_src[h * F + f];
            a2 += v * a_dst[h * F + f];
        }
        als[t] = a1; ald[t] = a2;
        s1 = a1;
    }
    // per-head block max (stride-8-preserving tree), then one atomic per head
    sh[tid] = s1;
    __syncthreads();
    #pragma unroll
    for (int off = 128; off >= 8; off >>= 1) {
        if (tid < off) sh[tid] = fmaxf(sh[tid], sh[tid + off]);
        __syncthreads();
    }
    if (tid < 8) {
        const float v = sh[tid];
        if (v > 0.f) atomicMax((int*)&Mh[tid], __float_as_int(v));  // int order == float order for >=0
    }
}

// ======================= fused gather: branch-free softmax + weighted sum + ELU =======================

template<int F>
__global__ void gat_gather(const int* __restrict__ rowptr, const int* __restrict__ esrc,
                           const float* __restrict__ als, const float* __restrict__ ald,
                           const float* __restrict__ Mh,
                           const float* __restrict__ Hf, const float* __restrict__ b,
                           float* __restrict__ out, int N) {
    const int t = blockIdx.x * blockDim.x + threadIdx.x;
    if (t >= N * GAT_H) return;
    const int dst = t >> 3, h = t & 7;
    const int beg = rowptr[dst], end = rowptr[dst + 1];
    const float adh = ald[t];
    float bnd = Mh[h] + adh;
    bnd = bnd > 0.f ? bnd : 0.2f * bnd;          // leaky(Mh+adh) >= segment max logit

    float s = 0.f;
    float4 acc[F / 4];
    #pragma unroll
    for (int j = 0; j < F / 4; ++j) acc[j] = make_float4(0.f, 0.f, 0.f, 0.f);

    // 1-iteration-ahead pipeline for src, logit AND the h-vector
    int src0 = esrc[beg];                        // deg >= 1 (self-loop)
    float al0 = als[src0 * GAT_H + h];
    float4 v0[F / 4];
    {
        const float4* hp = reinterpret_cast<const float4*>(Hf + ((size_t)src0 * GAT_H + h) * F);
        #pragma unroll
        for (int j = 0; j < F / 4; ++j) v0[j] = hp[j];
    }

    #pragma unroll 2
    for (int i = beg; i < end; ++i) {
        const int inext = (i + 1 < end) ? i + 1 : i;
        const int src1 = esrc[inext];
        const float al1 = als[src1 * GAT_H + h];
        float4 v1[F / 4];
        const float4* hp = reinterpret_cast<const float4*>(Hf + ((size_t)src1 * GAT_H + h) * F);
        #pragma unroll
        for (int j = 0; j < F / 4; ++j) v1[j] = hp[j];

        float x = al0 + adh;
        x = x > 0.f ? x : 0.2f * x;              // leaky_relu(0.2)
        const float p = __expf(x - bnd);
        s += p;
        #pragma unroll
        for (int j = 0; j < F / 4; ++j) {
            acc[j].x += p * v0[j].x; acc[j].y += p * v0[j].y;
            acc[j].z += p * v0[j].z; acc[j].w += p * v0[j].w;
        }
        al0 = al1;
        #pragma unroll
        for (int j = 0; j < F / 4; ++j) v0[j] = v1[j];
    }

    const float inv = 1.f / s;                   // s > 0 (self-loop term)
    #pragma unroll
    for (int j = 0; j < F / 4; ++j) {
        const float o[4] = {acc[j].x, acc[j].y, acc[j].z, acc[j].w};
        #pragma unroll
        for (int q = 0; q < 4; ++q) {
            const float val = o[q] * inv + b[h * F + 4 * j + q];
            out[((size_t)dst * GAT_H + h) * F + 4 * j + q] =
                val > 0.f ? val : expm1f(val);   // ELU
        }
    }
}

// ======================= pooling (sorted batch -> binary search) + MLP, fused =======================

__global__ __launch_bounds__(256) void pool_mlp_kernel(
        const float* __restrict__ A, const int* __restrict__ batch,
        const float* __restrict__ fc1w, const float* __restrict__ fc1b,
        const float* __restrict__ fc2w, const float* __restrict__ fc2b,
        float* __restrict__ out, int N) {
    const int g = blockIdx.x;
    int lo, hi;
    {
        int l = 0, h2 = N;
        while (l < h2) { const int mid = (l + h2) >> 1; if (batch[mid] < g) l = mid + 1; else h2 = mid; }
        lo = l;
        h2 = N;
        while (l < h2) { const int mid = (l + h2) >> 1; if (batch[mid] < g + 1) l = mid + 1; else h2 = mid; }
        hi = l;
    }
    __shared__ float part[256];
    __shared__ float pl[128];
    __shared__ float red2[32];
    const int tid = threadIdx.x;
    const int c = tid & 127, half = tid >> 7;
    float acc = 0.f;
    for (int n = lo + half; n < hi; n += 2) acc += A[(size_t)n * 128 + c];
    part[tid] = acc;
    __syncthreads();
    if (tid < 128) {
        const float tot = part[tid] + part[tid + 128];
        const float cntf = (float)(hi - lo);
        pl[tid] = tot / fmaxf(cntf, 1.f);
    }
    __syncthreads();
    if (tid < 32) {
        float a = fc1b[tid];
        for (int k = 0; k < 128; ++k) a += pl[k] * fc1w[k * 32 + tid];
        a = fmaxf(a, 0.f);
        red2[tid] = a * fc2w[tid];
    }
    __syncthreads();
    if (tid == 0) {
        float sum = fc2b[0];
        for (int k = 0; k < 32; ++k) sum += red2[k];
        out[g] = sum;
    }
}

// ======================= launch =======================

extern "C" void kernel_launch(void* const* d_in, const int* in_sizes, int n_in,
                              void* d_out, int out_size, void* d_ws, size_t ws_size,
                              hipStream_t stream) {
    const float* x     = (const float*)d_in[0];
    const int*   ei    = (const int*)  d_in[1];
    const int*   batch = (const int*)  d_in[2];
    const float* W1 = (const float*)d_in[3],  *as1 = (const float*)d_in[4],
               *ad1 = (const float*)d_in[5],  *b1  = (const float*)d_in[6];
    const float* W2 = (const float*)d_in[7],  *as2 = (const float*)d_in[8],
               *ad2 = (const float*)d_in[9],  *b2  = (const float*)d_in[10];
    const float* W3 = (const float*)d_in[11], *as3 = (const float*)d_in[12],
               *ad3 = (const float*)d_in[13], *b3  = (const float*)d_in[14];
    const float* fc1w = (const float*)d_in[15], *fc1b = (const float*)d_in[16];
    const float* fc2w = (const float*)d_in[17], *fc2b = (const float*)d_in[18];

    const int N  = in_sizes[0] / 16;     // 50000
    const int NE = in_sizes[1] / 2;      // 800000
    const int NG = out_size;             // 256
    const int ET = NE + N;               // edges incl. self-loops

    // workspace layout (4-byte elements)
    float* ws = (float*)d_ws;
    size_t off = 0;
    float* A    = ws + off; off += (size_t)N * 128;
    float* B    = ws + off; off += (size_t)N * 128;
    float* als  = ws + off; off += (size_t)N * GAT_H;
    float* ald  = ws + off; off += (size_t)N * GAT_H;
    float* Mh   = ws + off; off += 3 * GAT_H;          // per-layer global head max
    int* deg    = (int*)(ws + off); off += N;
    int* rowptr = (int*)(ws + off); off += N + 1;
    int* woff   = (int*)(ws + off); off += N;
    int* esrc   = (int*)(ws + off); off += ET;

    // ---- CSR build (graph identical for all 3 layers) ----
    hipMemsetAsync(deg, 0, (size_t)N * sizeof(int), stream);
    hipMemsetAsync(Mh, 0, 3 * GAT_H * sizeof(float), stream);
    hist_kernel<<<(ET + 255) / 256, 256, 0, stream>>>(ei, deg, NE, N);
    scan_kernel<<<1, 1024, 0, stream>>>(deg, rowptr, N);
    copy_int_kernel<<<(N + 255) / 256, 256, 0, stream>>>(rowptr, woff, N);
    scatter_kernel<<<(ET + 255) / 256, 256, 0, stream>>>(ei, woff, esrc, NE, N);

    const int NH = N * GAT_H;
    const int NHB = (NH + 255) / 256;
    const int NB = (N + 63) / 64;

    // ---- layer 1: 16 -> 8x8 ----
    matmul_tile<16, 64, 16><<<NB, 256, 0, stream>>>(x, W1, B, N);
    attnlogit_kernel<<<NHB, 256, 0, stream>>>(B, as1, ad1, als, ald, Mh, N, 8);
    gat_gather<8><<<NHB, 256, 0, stream>>>(rowptr, esrc, als, ald, Mh, B, b1, A, N);

    // ---- layer 2: 64 -> 8x16 ----
    matmul_tile<64, 128, 32><<<NB, 256, 0, stream>>>(A, W2, B, N);
    attnlogit_kernel<<<NHB, 256, 0, stream>>>(B, as2, ad2, als, ald, Mh + GAT_H, N, 16);
    gat_gather<16><<<NHB, 256, 0, stream>>>(rowptr, esrc, als, ald, Mh + GAT_H, B, b2, A, N);

    // ---- layer 3: 128 -> 8x16 ----
    matmul_tile<128, 128, 32><<<NB, 256, 0, stream>>>(A, W3, B, N);
    attnlogit_kernel<<<NHB, 256, 0, stream>>>(B, as3, ad3, als, ald, Mh + 2 * GAT_H, N, 16);
    gat_gather<16><<<NHB, 256, 0, stream>>>(rowptr, esrc, als, ald, Mh + 2 * GAT_H, B, b3, A, N);

    // ---- pool + MLP ----
    pool_mlp_kernel<<<NG, 256, 0, stream>>>(A, batch, fc1w, fc1b, fc2w, fc2b,
                                            (float*)d_out, N);
}

// Round 6
// 461.152 us; speedup vs baseline: 1.7043x; 1.3578x over previous
//
#include <hip/hip_runtime.h>
#include <hip/hip_bf16.h>
#include <cstdint>
#include <cstddef>

#define GAT_H 8

// fp32 -> bf16 with round-to-nearest-even, as raw ushort bits
__device__ __forceinline__ unsigned bf16r(float x) {
    const unsigned u = __float_as_uint(x);
    return (u + 0x7fffu + ((u >> 16) & 1u)) >> 16;
}
#define B2F_LO(u) __uint_as_float((u) << 16)
#define B2F_HI(u) __uint_as_float((u) & 0xffff0000u)

// ======================= CSR build (once per call) =======================

__global__ void hist_kernel(const int* __restrict__ ei, int* __restrict__ deg,
                            int nE, int nN) {
    const int e = blockIdx.x * blockDim.x + threadIdx.x;
    if (e >= nE + nN) return;
    const int dst = (e < nE) ? ei[nE + e] : (e - nE);   // self-loop tail
    atomicAdd(&deg[dst], 1);
}

// single-workgroup exclusive scan: rowptr[0]=0, rowptr[i+1]=sum(deg[0..i])
__global__ __launch_bounds__(1024) void scan_kernel(const int* __restrict__ deg,
                                                    int* __restrict__ rowptr, int N) {
    __shared__ int wsum[16];
    __shared__ int carry;
    const int tid = threadIdx.x;
    const int lane = tid & 63, wid = tid >> 6;
    if (tid == 0) carry = 0;
    __syncthreads();
    for (int base = 0; base < N; base += 1024) {
        const int i = base + tid;
        int incl = (i < N) ? deg[i] : 0;
        #pragma unroll
        for (int d = 1; d < 64; d <<= 1) {
            const int t = __shfl_up(incl, d, 64);
            if (lane >= d) incl += t;
        }
        if (lane == 63) wsum[wid] = incl;
        __syncthreads();
        if (tid == 0) {
            int run = carry;
            #pragma unroll
            for (int w = 0; w < 16; ++w) { const int t2 = wsum[w]; wsum[w] = run; run += t2; }
            carry = run;
        }
        __syncthreads();
        if (i < N) rowptr[i + 1] = wsum[wid] + incl;
        __syncthreads();
    }
    if (tid == 0) rowptr[0] = 0;
}

__global__ void copy_int_kernel(const int* __restrict__ a, int* __restrict__ b, int n) {
    const int i = blockIdx.x * blockDim.x + threadIdx.x;
    if (i < n) b[i] = a[i];
}

__global__ void scatter_kernel(const int* __restrict__ ei, int* __restrict__ woff,
                               int* __restrict__ esrc, int nE, int nN) {
    const int e = blockIdx.x * blockDim.x + threadIdx.x;
    if (e >= nE + nN) return;
    int src, dst;
    if (e < nE) { src = ei[e]; dst = ei[nE + e]; }
    else        { src = dst = e - nE; }
    const int pos = atomicAdd(&woff[dst], 1);
    esrc[pos] = src;
}

// ======================= node matmul (register-blocked, LDS-staged) =======================
// Writes fp32 h (for exact logits) AND an RNE bf16 copy (for the gather's value path).

template<int D, int C, int KK>
__global__ __launch_bounds__(256) void matmul_tile(const float* __restrict__ X,
                                                   const float* __restrict__ W,
                                                   float* __restrict__ Hout,
                                                   unsigned short* __restrict__ Hb,
                                                   int N) {
    constexpr int CG  = C / 8;
    constexpr int NGR = 256 / CG;
    constexpr int NPT = 64 / NGR;
    constexpr int XS  = KK + 4;
    __shared__ float xs[64][XS];
    __shared__ float wsh[KK][C];

    const int n0 = blockIdx.x * 64;
    const int tid = threadIdx.x;
    const int cg = tid % CG, ngr = tid / CG;
    const int c0 = cg * 8;

    float acc[NPT][8];
    #pragma unroll
    for (int i = 0; i < NPT; ++i)
        #pragma unroll
        for (int j = 0; j < 8; ++j) acc[i][j] = 0.f;

    for (int k0 = 0; k0 < D; k0 += KK) {
        for (int t = tid; t < 64 * (KK / 4); t += 256) {
            const int row = t / (KK / 4), c4 = (t % (KK / 4)) * 4;
            const int n = n0 + row;
            float4 v = make_float4(0.f, 0.f, 0.f, 0.f);
            if (n < N) v = *reinterpret_cast<const float4*>(&X[(size_t)n * D + k0 + c4]);
            *reinterpret_cast<float4*>(&xs[row][c4]) = v;
        }
        for (int t = tid; t < KK * (C / 4); t += 256) {
            const int row = t / (C / 4), c4 = (t % (C / 4)) * 4;
            *reinterpret_cast<float4*>(&wsh[row][c4]) =
                *reinterpret_cast<const float4*>(&W[(size_t)(k0 + row) * C + c4]);
        }
        __syncthreads();

        #pragma unroll
        for (int k4 = 0; k4 < KK; k4 += 4) {
            float4 xv[NPT];
            #pragma unroll
            for (int i = 0; i < NPT; ++i)
                xv[i] = *reinterpret_cast<const float4*>(&xs[ngr * NPT + i][k4]);
            #pragma unroll
            for (int kk = 0; kk < 4; ++kk) {
                const float4 w0 = *reinterpret_cast<const float4*>(&wsh[k4 + kk][c0]);
                const float4 w1 = *reinterpret_cast<const float4*>(&wsh[k4 + kk][c0 + 4]);
                #pragma unroll
                for (int i = 0; i < NPT; ++i) {
                    const float xk = (kk == 0) ? xv[i].x : (kk == 1) ? xv[i].y
                                   : (kk == 2) ? xv[i].z : xv[i].w;
                    acc[i][0] += xk * w0.x; acc[i][1] += xk * w0.y;
                    acc[i][2] += xk * w0.z; acc[i][3] += xk * w0.w;
                    acc[i][4] += xk * w1.x; acc[i][5] += xk * w1.y;
                    acc[i][6] += xk * w1.z; acc[i][7] += xk * w1.w;
                }
            }
        }
        __syncthreads();
    }

    #pragma unroll
    for (int i = 0; i < NPT; ++i) {
        const int n = n0 + ngr * NPT + i;
        if (n < N) {
            float4 o0 = make_float4(acc[i][0], acc[i][1], acc[i][2], acc[i][3]);
            float4 o1 = make_float4(acc[i][4], acc[i][5], acc[i][6], acc[i][7]);
            *reinterpret_cast<float4*>(&Hout[(size_t)n * C + c0])     = o0;
            *reinterpret_cast<float4*>(&Hout[(size_t)n * C + c0 + 4]) = o1;
            uint4 pk;
            pk.x = bf16r(acc[i][0]) | (bf16r(acc[i][1]) << 16);
            pk.y = bf16r(acc[i][2]) | (bf16r(acc[i][3]) << 16);
            pk.z = bf16r(acc[i][4]) | (bf16r(acc[i][5]) << 16);
            pk.w = bf16r(acc[i][6]) | (bf16r(acc[i][7]) << 16);
            *reinterpret_cast<uint4*>(&Hb[(size_t)n * C + c0]) = pk;
        }
    }
}

// ======================= attention logits + global per-head max of als =======================
// Mh[h] must be 0-initialized; after this kernel Mh[h] = max(0, max_n als[n,h]).
// (Any per-(dst,h) value >= segment max gives an identical softmax - shift invariance.)

__global__ void attnlogit_kernel(const float* __restrict__ Hf,
                                 const float* __restrict__ a_src,
                                 const float* __restrict__ a_dst,
                                 float* __restrict__ als, float* __restrict__ ald,
                                 float* __restrict__ Mh, int N, int F) {
    __shared__ float sh[256];
    const int t = blockIdx.x * blockDim.x + threadIdx.x;
    const int tid = threadIdx.x;
    float s1 = -1e30f;
    if (t < N * GAT_H) {
        const int n = t / GAT_H, h = t % GAT_H;
        const float* hp = Hf + ((size_t)n * GAT_H + h) * F;
        float a1 = 0.f, a2 = 0.f;
        for (int f = 0; f < F; ++f) {
            const float v = hp[f];
            a1 += v * a_src[h * F + f];
            a2 += v * a_dst[h * F + f];
        }
        als[t] = a1; ald[t] = a2;
        s1 = a1;
    }
    sh[tid] = s1;
    __syncthreads();
    #pragma unroll
    for (int off = 128; off >= 8; off >>= 1) {
        if (tid < off) sh[tid] = fmaxf(sh[tid], sh[tid + off]);
        __syncthreads();
    }
    if (tid < 8) {
        const float v = sh[tid];
        if (v > 0.f) atomicMax((int*)&Mh[tid], __float_as_int(v));  // int order == float order for >=0
    }
}

// ======================= fused gather: branch-free softmax + bf16 weighted sum + ELU =======================

template<int F>
__global__ void gat_gather(const int* __restrict__ rowptr, const int* __restrict__ esrc,
                           const float* __restrict__ als, const float* __restrict__ ald,
                           const float* __restrict__ Mh,
                           const unsigned short* __restrict__ Hb, const float* __restrict__ b,
                           float* __restrict__ out, int N) {
    const int t = blockIdx.x * blockDim.x + threadIdx.x;
    if (t >= N * GAT_H) return;
    const int dst = t >> 3, h = t & 7;
    const int beg = rowptr[dst], end = rowptr[dst + 1];
    const float adh = ald[t];
    float bnd = Mh[h] + adh;
    bnd = bnd > 0.f ? bnd : 0.2f * bnd;          // leaky(Mh+adh) >= segment max logit

    constexpr int NW = F / 2;                    // u32 words per head-slice
    float s = 0.f;
    float acc[F];
    #pragma unroll
    for (int j = 0; j < F; ++j) acc[j] = 0.f;

    // one-ahead prefetch of src index + logit only (shallow pipeline)
    int src0 = esrc[beg];                        // deg >= 1 (self-loop)
    float al0 = als[src0 * GAT_H + h];
    for (int i = beg; i < end; ++i) {
        // bf16 value vector: F/2 u32 words = F*2 bytes
        union { uint4 q[NW / 4]; unsigned w[NW]; } v;
        const uint4* hq = reinterpret_cast<const uint4*>(Hb + ((size_t)src0 * GAT_H + h) * F);
        #pragma unroll
        for (int j = 0; j < NW / 4; ++j) v.q[j] = hq[j];

        const int inext = (i + 1 < end) ? i + 1 : i;
        const int src1 = esrc[inext];
        const float al1 = als[src1 * GAT_H + h];

        float x = al0 + adh;
        x = x > 0.f ? x : 0.2f * x;              // leaky_relu(0.2)
        const float p = __expf(x - bnd);
        s += p;
        #pragma unroll
        for (int j = 0; j < NW; ++j) {
            acc[2 * j]     += p * B2F_LO(v.w[j]);
            acc[2 * j + 1] += p * B2F_HI(v.w[j]);
        }
        src0 = src1; al0 = al1;
    }

    const float inv = 1.f / s;                   // s > 0 (self-loop term)
    float4 o[F / 4];
    #pragma unroll
    for (int j = 0; j < F / 4; ++j) {
        float vv[4];
        #pragma unroll
        for (int q = 0; q < 4; ++q) {
            const float val = acc[4 * j + q] * inv + b[h * F + 4 * j + q];
            vv[q] = val > 0.f ? val : expm1f(val);   // ELU
        }
        o[j] = make_float4(vv[0], vv[1], vv[2], vv[3]);
        *reinterpret_cast<float4*>(&out[((size_t)dst * GAT_H + h) * F + 4 * j]) = o[j];
    }
}

// ======================= pooling (sorted batch -> binary search) + MLP, fused =======================

__global__ __launch_bounds__(256) void pool_mlp_kernel(
        const float* __restrict__ A, const int* __restrict__ batch,
        const float* __restrict__ fc1w, const float* __restrict__ fc1b,
        const float* __restrict__ fc2w, const float* __restrict__ fc2b,
        float* __restrict__ out, int N) {
    const int g = blockIdx.x;
    int lo, hi;
    {
        int l = 0, h2 = N;
        while (l < h2) { const int mid = (l + h2) >> 1; if (batch[mid] < g) l = mid + 1; else h2 = mid; }
        lo = l;
        h2 = N;
        while (l < h2) { const int mid = (l + h2) >> 1; if (batch[mid] < g + 1) l = mid + 1; else h2 = mid; }
        hi = l;
    }
    __shared__ float4 part[8][32];
    __shared__ float pl[128];
    __shared__ float red2[32];
    const int tid = threadIdx.x;
    const int c4 = (tid & 31) * 4, r = tid >> 5;       // 8 rows in flight, float4 cols
    float4 acc = make_float4(0.f, 0.f, 0.f, 0.f);
    for (int n = lo + r; n < hi; n += 8) {
        const float4 v = *reinterpret_cast<const float4*>(&A[(size_t)n * 128 + c4]);
        acc.x += v.x; acc.y += v.y; acc.z += v.z; acc.w += v.w;
    }
    part[r][tid & 31] = acc;
    __syncthreads();
    if (tid < 32) {
        float4 s = part[0][tid];
        #pragma unroll
        for (int rr = 1; rr < 8; ++rr) {
            const float4 v = part[rr][tid];
            s.x += v.x; s.y += v.y; s.z += v.z; s.w += v.w;
        }
        const float invc = 1.f / fmaxf((float)(hi - lo), 1.f);
        pl[tid * 4]     = s.x * invc;
        pl[tid * 4 + 1] = s.y * invc;
        pl[tid * 4 + 2] = s.z * invc;
        pl[tid * 4 + 3] = s.w * invc;
    }
    __syncthreads();
    if (tid < 32) {
        float a = fc1b[tid];
        for (int k = 0; k < 128; ++k) a += pl[k] * fc1w[k * 32 + tid];
        a = fmaxf(a, 0.f);
        red2[tid] = a * fc2w[tid];
    }
    __syncthreads();
    if (tid == 0) {
        float sum = fc2b[0];
        for (int k = 0; k < 32; ++k) sum += red2[k];
        out[g] = sum;
    }
}

// ======================= launch =======================

extern "C" void kernel_launch(void* const* d_in, const int* in_sizes, int n_in,
                              void* d_out, int out_size, void* d_ws, size_t ws_size,
                              hipStream_t stream) {
    const float* x     = (const float*)d_in[0];
    const int*   ei    = (const int*)  d_in[1];
    const int*   batch = (const int*)  d_in[2];
    const float* W1 = (const float*)d_in[3],  *as1 = (const float*)d_in[4],
               *ad1 = (const float*)d_in[5],  *b1  = (const float*)d_in[6];
    const float* W2 = (const float*)d_in[7],  *as2 = (const float*)d_in[8],
               *ad2 = (const float*)d_in[9],  *b2  = (const float*)d_in[10];
    const float* W3 = (const float*)d_in[11], *as3 = (const float*)d_in[12],
               *ad3 = (const float*)d_in[13], *b3  = (const float*)d_in[14];
    const float* fc1w = (const float*)d_in[15], *fc1b = (const float*)d_in[16];
    const float* fc2w = (const float*)d_in[17], *fc2b = (const float*)d_in[18];

    const int N  = in_sizes[0] / 16;     // 50000
    const int NE = in_sizes[1] / 2;      // 800000
    const int NG = out_size;             // 256
    const int ET = NE + N;               // edges incl. self-loops

    // workspace layout (keep 16B alignment for everything before rowptr)
    float* ws = (float*)d_ws;
    size_t off = 0;
    float* A    = ws + off; off += (size_t)N * 128;
    float* B    = ws + off; off += (size_t)N * 128;
    unsigned short* Hb = (unsigned short*)(ws + off); off += (size_t)N * 64;  // bf16 h copy
    float* als  = ws + off; off += (size_t)N * GAT_H;
    float* ald  = ws + off; off += (size_t)N * GAT_H;
    float* Mh   = ws + off; off += 3 * GAT_H;          // per-layer global head max (24 floats, 96B)
    int* deg    = (int*)(ws + off); off += N;
    int* rowptr = (int*)(ws + off); off += N + 1;
    int* woff   = (int*)(ws + off); off += N;
    int* esrc   = (int*)(ws + off); off += ET;

    // ---- CSR build (graph identical for all 3 layers) ----
    hipMemsetAsync(deg, 0, (size_t)N * sizeof(int), stream);
    hipMemsetAsync(Mh, 0, 3 * GAT_H * sizeof(float), stream);
    hist_kernel<<<(ET + 255) / 256, 256, 0, stream>>>(ei, deg, NE, N);
    scan_kernel<<<1, 1024, 0, stream>>>(deg, rowptr, N);
    copy_int_kernel<<<(N + 255) / 256, 256, 0, stream>>>(rowptr, woff, N);
    scatter_kernel<<<(ET + 255) / 256, 256, 0, stream>>>(ei, woff, esrc, NE, N);

    const int NH = N * GAT_H;
    const int NHB = (NH + 255) / 256;
    const int NB = (N + 63) / 64;

    // ---- layer 1: 16 -> 8x8 ----
    matmul_tile<16, 64, 16><<<NB, 256, 0, stream>>>(x, W1, B, Hb, N);
    attnlogit_kernel<<<NHB, 256, 0, stream>>>(B, as1, ad1, als, ald, Mh, N, 8);
    gat_gather<8><<<NHB, 256, 0, stream>>>(rowptr, esrc, als, ald, Mh, Hb, b1, A, N);

    // ---- layer 2: 64 -> 8x16 ----
    matmul_tile<64, 128, 32><<<NB, 256, 0, stream>>>(A, W2, B, Hb, N);
    attnlogit_kernel<<<NHB, 256, 0, stream>>>(B, as2, ad2, als, ald, Mh + GAT_H, N, 16);
    gat_gather<16><<<NHB, 256, 0, stream>>>(rowptr, esrc, als, ald, Mh + GAT_H, Hb, b2, A, N);

    // ---- layer 3: 128 -> 8x16 ----
    matmul_tile<128, 128, 32><<<NB, 256, 0, stream>>>(A, W3, B, Hb, N);
    attnlogit_kernel<<<NHB, 256, 0, stream>>>(B, as3, ad3, als, ald, Mh + 2 * GAT_H, N, 16);
    gat_gather<16><<<NHB, 256, 0, stream>>>(rowptr, esrc, als, ald, Mh + 2 * GAT_H, Hb, b3, A, N);

    // ---- pool + MLP ----
    pool_mlp_kernel<<<NG, 256, 0, stream>>>(A, batch, fc1w, fc1b, fc2w, fc2b,
                                            (float*)d_out, N);
}

// Round 7
// 344.683 us; speedup vs baseline: 2.2802x; 1.3379x over previous
//
#include <hip/hip_runtime.h>
#include <hip/hip_bf16.h>
#include <cstdint>
#include <cstddef>

#define GAT_H 8

// fp32 -> bf16 with round-to-nearest-even, as raw ushort bits
__device__ __forceinline__ unsigned bf16r(float x) {
    const unsigned u = __float_as_uint(x);
    return (u + 0x7fffu + ((u >> 16) & 1u)) >> 16;
}
#define B2F_LO(u) __uint_as_float((u) << 16)
#define B2F_HI(u) __uint_as_float((u) & 0xffff0000u)

// ======================= CSR build (once per call) =======================

__global__ void hist_kernel(const int* __restrict__ ei, int* __restrict__ deg,
                            int nE, int nN) {
    const int e = blockIdx.x * blockDim.x + threadIdx.x;
    if (e >= nE + nN) return;
    const int dst = (e < nE) ? ei[nE + e] : (e - nE);   // self-loop tail
    atomicAdd(&deg[dst], 1);
}

// ---- 3-phase scan over deg (chunk = 1024 per block) ----
__global__ __launch_bounds__(256) void scanA_kernel(const int* __restrict__ deg,
                                                    int* __restrict__ rowptr,
                                                    int* __restrict__ part, int N) {
    __shared__ int wtot[4];
    const int tid = threadIdx.x;
    const int lane = tid & 63, wid = tid >> 6;
    const int i0 = blockIdx.x * 1024 + tid * 4;
    int a0 = 0, a1 = 0, a2 = 0, a3 = 0;
    if (i0 + 3 < N) {
        const int4 v = *reinterpret_cast<const int4*>(&deg[i0]);
        a0 = v.x; a1 = v.y; a2 = v.z; a3 = v.w;
    } else {
        if (i0     < N) a0 = deg[i0];
        if (i0 + 1 < N) a1 = deg[i0 + 1];
        if (i0 + 2 < N) a2 = deg[i0 + 2];
        if (i0 + 3 < N) a3 = deg[i0 + 3];
    }
    const int s1 = a0, s2 = s1 + a1, s3 = s2 + a2, s4 = s3 + a3;
    int incl = s4;
    #pragma unroll
    for (int d = 1; d < 64; d <<= 1) {
        const int t = __shfl_up(incl, d, 64);
        if (lane >= d) incl += t;
    }
    if (lane == 63) wtot[wid] = incl;
    __syncthreads();
    int woffs = 0;
    #pragma unroll
    for (int w = 0; w < 4; ++w) if (w < wid) woffs += wtot[w];
    const int excl = woffs + incl - s4;
    if (i0     < N) rowptr[i0 + 1] = excl + s1;
    if (i0 + 1 < N) rowptr[i0 + 2] = excl + s2;
    if (i0 + 2 < N) rowptr[i0 + 3] = excl + s3;
    if (i0 + 3 < N) rowptr[i0 + 4] = excl + s4;
    if (tid == 255) part[blockIdx.x] = woffs + incl;
}

__global__ void scanB_kernel(int* __restrict__ part, int nb) {   // nb <= 64, one wave
    const int lane = threadIdx.x;
    const int v = (lane < nb) ? part[lane] : 0;
    int incl = v;
    #pragma unroll
    for (int d = 1; d < 64; d <<= 1) {
        const int t = __shfl_up(incl, d, 64);
        if (lane >= d) incl += t;
    }
    if (lane < nb) part[lane] = incl - v;   // exclusive
}

__global__ void scanC_kernel(const int* __restrict__ deg, int* __restrict__ rowptr,
                             int* __restrict__ woff, const int* __restrict__ part, int N) {
    const int i = blockIdx.x * blockDim.x + threadIdx.x;
    if (i >= N) return;
    const int add = part[i >> 10];
    const int incl = rowptr[i + 1] + add;
    rowptr[i + 1] = incl;
    woff[i] = incl - deg[i];
    if (i == 0) rowptr[0] = 0;
}

__global__ void scatter_kernel(const int* __restrict__ ei, int* __restrict__ woff,
                               int* __restrict__ esrc, int nE, int nN) {
    const int e = blockIdx.x * blockDim.x + threadIdx.x;
    if (e >= nE + nN) return;
    int src, dst;
    if (e < nE) { src = ei[e]; dst = ei[nE + e]; }
    else        { src = dst = e - nE; }
    const int pos = atomicAdd(&woff[dst], 1);
    __builtin_nontemporal_store(src, &esrc[pos]);   // no write-allocate line bounce
}

// ======================= fused node matmul + attention logits + head max =======================
// Computes h = X@W in registers, writes ONLY the bf16 copy (gather's value path),
// and computes als/ald = <h, a_src/a_dst> per (node,head) from the registers
// (exact fp32), plus Mh[h] = max(0, max_n als[n,h]) via LDS+global atomicMax.

template<int D, int C, int KK, int F>
__global__ __launch_bounds__(256) void matmul_fused(
        const float* __restrict__ X, const float* __restrict__ W,
        const float* __restrict__ a_src, const float* __restrict__ a_dst,
        unsigned short* __restrict__ Hb,
        float* __restrict__ als, float* __restrict__ ald,
        float* __restrict__ Mh, int N) {
    constexpr int CG  = C / 8;
    constexpr int NGR = 256 / CG;
    constexpr int NPT = 64 / NGR;
    constexpr int XS  = KK + 4;
    __shared__ float xs[64][XS];
    __shared__ float wsh[KK][C];
    __shared__ float2 phl[64][GAT_H];   // odd-half partial (src,dst) logits (F==16 only)
    __shared__ int bmax[GAT_H];

    const int n0 = blockIdx.x * 64;
    const int tid = threadIdx.x;
    const int cg = tid % CG, ngr = tid / CG;
    const int c0 = cg * 8;
    if (tid < GAT_H) bmax[tid] = 0;

    float acc[NPT][8];
    #pragma unroll
    for (int i = 0; i < NPT; ++i)
        #pragma unroll
        for (int j = 0; j < 8; ++j) acc[i][j] = 0.f;

    for (int k0 = 0; k0 < D; k0 += KK) {
        for (int t = tid; t < 64 * (KK / 4); t += 256) {
            const int row = t / (KK / 4), c4 = (t % (KK / 4)) * 4;
            const int n = n0 + row;
            float4 v = make_float4(0.f, 0.f, 0.f, 0.f);
            if (n < N) v = *reinterpret_cast<const float4*>(&X[(size_t)n * D + k0 + c4]);
            *reinterpret_cast<float4*>(&xs[row][c4]) = v;
        }
        for (int t = tid; t < KK * (C / 4); t += 256) {
            const int row = t / (C / 4), c4 = (t % (C / 4)) * 4;
            *reinterpret_cast<float4*>(&wsh[row][c4]) =
                *reinterpret_cast<const float4*>(&W[(size_t)(k0 + row) * C + c4]);
        }
        __syncthreads();

        #pragma unroll
        for (int k4 = 0; k4 < KK; k4 += 4) {
            float4 xv[NPT];
            #pragma unroll
            for (int i = 0; i < NPT; ++i)
                xv[i] = *reinterpret_cast<const float4*>(&xs[ngr * NPT + i][k4]);
            #pragma unroll
            for (int kk = 0; kk < 4; ++kk) {
                const float4 w0 = *reinterpret_cast<const float4*>(&wsh[k4 + kk][c0]);
                const float4 w1 = *reinterpret_cast<const float4*>(&wsh[k4 + kk][c0 + 4]);
                #pragma unroll
                for (int i = 0; i < NPT; ++i) {
                    const float xk = (kk == 0) ? xv[i].x : (kk == 1) ? xv[i].y
                                   : (kk == 2) ? xv[i].z : xv[i].w;
                    acc[i][0] += xk * w0.x; acc[i][1] += xk * w0.y;
                    acc[i][2] += xk * w0.z; acc[i][3] += xk * w0.w;
                    acc[i][4] += xk * w1.x; acc[i][5] += xk * w1.y;
                    acc[i][6] += xk * w1.z; acc[i][7] += xk * w1.w;
                }
            }
        }
        __syncthreads();
    }

    // ---- epilogue: bf16 store + fused logits ----
    const int h   = c0 / F;          // head owning these 8 cols
    const int off = c0 % F;          // 0 (F=8) or 0/8 (F=16)
    float asr[8], adr[8];
    #pragma unroll
    for (int q = 0; q < 8; ++q) {
        asr[q] = a_src[h * F + off + q];
        adr[q] = a_dst[h * F + off + q];
    }

    float ps[NPT], pd[NPT];
    #pragma unroll
    for (int i = 0; i < NPT; ++i) {
        float s = 0.f, d2 = 0.f;
        #pragma unroll
        for (int q = 0; q < 8; ++q) { s += acc[i][q] * asr[q]; d2 += acc[i][q] * adr[q]; }
        ps[i] = s; pd[i] = d2;
        const int n = n0 + ngr * NPT + i;
        if (n < N) {
            uint4 pk;
            pk.x = bf16r(acc[i][0]) | (bf16r(acc[i][1]) << 16);
            pk.y = bf16r(acc[i][2]) | (bf16r(acc[i][3]) << 16);
            pk.z = bf16r(acc[i][4]) | (bf16r(acc[i][5]) << 16);
            pk.w = bf16r(acc[i][6]) | (bf16r(acc[i][7]) << 16);
            *reinterpret_cast<uint4*>(&Hb[(size_t)n * C + c0]) = pk;
        }
    }

    if constexpr (F == 16) {
        if (cg & 1) {
            #pragma unroll
            for (int i = 0; i < NPT; ++i)
                phl[ngr * NPT + i][h] = make_float2(ps[i], pd[i]);
        }
        __syncthreads();
        if (!(cg & 1)) {
            #pragma unroll
            for (int i = 0; i < NPT; ++i) {
                const int nl = ngr * NPT + i;
                const int n = n0 + nl;
                const float al = ps[i] + phl[nl][h].x;
                const float ad = pd[i] + phl[nl][h].y;
                if (n < N) {
                    als[(size_t)n * GAT_H + h] = al;
                    ald[(size_t)n * GAT_H + h] = ad;
                    if (al > 0.f) atomicMax(&bmax[h], __float_as_int(al));
                }
            }
        }
    } else {
        #pragma unroll
        for (int i = 0; i < NPT; ++i) {
            const int n = n0 + ngr * NPT + i;
            if (n < N) {
                als[(size_t)n * GAT_H + h] = ps[i];
                ald[(size_t)n * GAT_H + h] = pd[i];
                if (ps[i] > 0.f) atomicMax(&bmax[h], __float_as_int(ps[i]));
            }
        }
    }
    __syncthreads();
    if (tid < GAT_H) {
        const int v = bmax[tid];
        if (v > 0) atomicMax((int*)&Mh[tid], v);   // int order == float order for >=0
    }
}

// ======================= fused gather: branch-free softmax + bf16 weighted sum + ELU =======================

template<int F>
__global__ void gat_gather(const int* __restrict__ rowptr, const int* __restrict__ esrc,
                           const float* __restrict__ als, const float* __restrict__ ald,
                           const float* __restrict__ Mh,
                           const unsigned short* __restrict__ Hb, const float* __restrict__ b,
                           float* __restrict__ out, int N) {
    const int t = blockIdx.x * blockDim.x + threadIdx.x;
    if (t >= N * GAT_H) return;
    const int dst = t >> 3, h = t & 7;
    const int beg = rowptr[dst], end = rowptr[dst + 1];
    const float adh = ald[t];
    float bnd = Mh[h] + adh;
    bnd = bnd > 0.f ? bnd : 0.2f * bnd;          // leaky(Mh+adh) >= segment max logit

    constexpr int NW = F / 2;                    // u32 words per head-slice
    float s = 0.f;
    float acc[F];
    #pragma unroll
    for (int j = 0; j < F; ++j) acc[j] = 0.f;

    // one-ahead prefetch of src index + logit (shallow pipeline)
    int src0 = esrc[beg];                        // deg >= 1 (self-loop)
    float al0 = als[src0 * GAT_H + h];
    for (int i = beg; i < end; ++i) {
        union { uint4 q[NW / 4]; unsigned w[NW]; } v;
        const uint4* hq = reinterpret_cast<const uint4*>(Hb + ((size_t)src0 * GAT_H + h) * F);
        #pragma unroll
        for (int j = 0; j < NW / 4; ++j) v.q[j] = hq[j];

        const int inext = (i + 1 < end) ? i + 1 : i;
        const int src1 = esrc[inext];
        const float al1 = als[src1 * GAT_H + h];

        float x = al0 + adh;
        x = x > 0.f ? x : 0.2f * x;              // leaky_relu(0.2)
        const float p = __expf(x - bnd);
        s += p;
        #pragma unroll
        for (int j = 0; j < NW; ++j) {
            acc[2 * j]     += p * B2F_LO(v.w[j]);
            acc[2 * j + 1] += p * B2F_HI(v.w[j]);
        }
        src0 = src1; al0 = al1;
    }

    const float inv = 1.f / s;                   // s > 0 (self-loop term)
    #pragma unroll
    for (int j = 0; j < F / 4; ++j) {
        float vv[4];
        #pragma unroll
        for (int q = 0; q < 4; ++q) {
            const float val = acc[4 * j + q] * inv + b[h * F + 4 * j + q];
            vv[q] = val > 0.f ? val : expm1f(val);   // ELU
        }
        *reinterpret_cast<float4*>(&out[((size_t)dst * GAT_H + h) * F + 4 * j]) =
            make_float4(vv[0], vv[1], vv[2], vv[3]);
    }
}

// ======================= pooling (sorted batch -> binary search) + MLP, fused =======================

__global__ __launch_bounds__(256) void pool_mlp_kernel(
        const float* __restrict__ A, const int* __restrict__ batch,
        const float* __restrict__ fc1w, const float* __restrict__ fc1b,
        const float* __restrict__ fc2w, const float* __restrict__ fc2b,
        float* __restrict__ out, int N) {
    const int g = blockIdx.x;
    int lo, hi;
    {
        int l = 0, h2 = N;
        while (l < h2) { const int mid = (l + h2) >> 1; if (batch[mid] < g) l = mid + 1; else h2 = mid; }
        lo = l;
        h2 = N;
        while (l < h2) { const int mid = (l + h2) >> 1; if (batch[mid] < g + 1) l = mid + 1; else h2 = mid; }
        hi = l;
    }
    __shared__ float4 part[8][32];
    __shared__ float pl[128];
    __shared__ float red2[32];
    const int tid = threadIdx.x;
    const int c4 = (tid & 31) * 4, r = tid >> 5;
    float4 acc = make_float4(0.f, 0.f, 0.f, 0.f);
    for (int n = lo + r; n < hi; n += 8) {
        const float4 v = *reinterpret_cast<const float4*>(&A[(size_t)n * 128 + c4]);
        acc.x += v.x; acc.y += v.y; acc.z += v.z; acc.w += v.w;
    }
    part[r][tid & 31] = acc;
    __syncthreads();
    if (tid < 32) {
        float4 s = part[0][tid];
        #pragma unroll
        for (int rr = 1; rr < 8; ++rr) {
            const float4 v = part[rr][tid];
            s.x += v.x; s.y += v.y; s.z += v.z; s.w += v.w;
        }
        const float invc = 1.f / fmaxf((float)(hi - lo), 1.f);
        pl[tid * 4]     = s.x * invc;
        pl[tid * 4 + 1] = s.y * invc;
        pl[tid * 4 + 2] = s.z * invc;
        pl[tid * 4 + 3] = s.w * invc;
    }
    __syncthreads();
    if (tid < 32) {
        float a = fc1b[tid];
        for (int k = 0; k < 128; ++k) a += pl[k] * fc1w[k * 32 + tid];
        a = fmaxf(a, 0.f);
        red2[tid] = a * fc2w[tid];
    }
    __syncthreads();
    if (tid == 0) {
        float sum = fc2b[0];
        for (int k = 0; k < 32; ++k) sum += red2[k];
        out[g] = sum;
    }
}

// ======================= launch =======================

extern "C" void kernel_launch(void* const* d_in, const int* in_sizes, int n_in,
                              void* d_out, int out_size, void* d_ws, size_t ws_size,
                              hipStream_t stream) {
    const float* x     = (const float*)d_in[0];
    const int*   ei    = (const int*)  d_in[1];
    const int*   batch = (const int*)  d_in[2];
    const float* W1 = (const float*)d_in[3],  *as1 = (const float*)d_in[4],
               *ad1 = (const float*)d_in[5],  *b1  = (const float*)d_in[6];
    const float* W2 = (const float*)d_in[7],  *as2 = (const float*)d_in[8],
               *ad2 = (const float*)d_in[9],  *b2  = (const float*)d_in[10];
    const float* W3 = (const float*)d_in[11], *as3 = (const float*)d_in[12],
               *ad3 = (const float*)d_in[13], *b3  = (const float*)d_in[14];
    const float* fc1w = (const float*)d_in[15], *fc1b = (const float*)d_in[16];
    const float* fc2w = (const float*)d_in[17], *fc2b = (const float*)d_in[18];

    const int N  = in_sizes[0] / 16;     // 50000
    const int NE = in_sizes[1] / 2;      // 800000
    const int NG = out_size;             // 256
    const int ET = NE + N;               // edges incl. self-loops

    // workspace layout (16B alignment maintained)
    float* ws = (float*)d_ws;
    size_t off = 0;
    float* A    = ws + off; off += (size_t)N * 128;
    unsigned short* Hb = (unsigned short*)(ws + off); off += (size_t)N * 64;  // bf16 h
    float* als  = ws + off; off += (size_t)N * GAT_H;
    float* ald  = ws + off; off += (size_t)N * GAT_H;
    float* Mh   = ws + off; off += 3 * GAT_H;          // per-layer global head max
    int* deg    = (int*)(ws + off); off += N;
    int* rowptr = (int*)(ws + off); off += N + 1;
    int* woff   = (int*)(ws + off); off += N;
    int* esrc   = (int*)(ws + off); off += ET;
    int* part   = (int*)(ws + off); off += 64;

    // ---- CSR build (graph identical for all 3 layers) ----
    const int NBS = (N + 1023) / 1024;                 // scan blocks (<= 64)
    hipMemsetAsync(deg, 0, (size_t)N * sizeof(int), stream);
    hipMemsetAsync(Mh, 0, 3 * GAT_H * sizeof(float), stream);
    hist_kernel<<<(ET + 255) / 256, 256, 0, stream>>>(ei, deg, NE, N);
    scanA_kernel<<<NBS, 256, 0, stream>>>(deg, rowptr, part, N);
    scanB_kernel<<<1, 64, 0, stream>>>(part, NBS);
    scanC_kernel<<<(N + 255) / 256, 256, 0, stream>>>(deg, rowptr, woff, part, N);
    scatter_kernel<<<(ET + 255) / 256, 256, 0, stream>>>(ei, woff, esrc, NE, N);

    const int NH = N * GAT_H;
    const int NHB = (NH + 255) / 256;
    const int NB = (N + 63) / 64;

    // ---- layer 1: 16 -> 8x8 ----
    matmul_fused<16, 64, 16, 8><<<NB, 256, 0, stream>>>(x, W1, as1, ad1, Hb, als, ald, Mh, N);
    gat_gather<8><<<NHB, 256, 0, stream>>>(rowptr, esrc, als, ald, Mh, Hb, b1, A, N);

    // ---- layer 2: 64 -> 8x16 ----
    matmul_fused<64, 128, 32, 16><<<NB, 256, 0, stream>>>(A, W2, as2, ad2, Hb, als, ald, Mh + GAT_H, N);
    gat_gather<16><<<NHB, 256, 0, stream>>>(rowptr, esrc, als, ald, Mh + GAT_H, Hb, b2, A, N);

    // ---- layer 3: 128 -> 8x16 ----
    matmul_fused<128, 128, 32, 16><<<NB, 256, 0, stream>>>(A, W3, as3, ad3, Hb, als, ald, Mh + 2 * GAT_H, N);
    gat_gather<16><<<NHB, 256, 0, stream>>>(rowptr, esrc, als, ald, Mh + 2 * GAT_H, Hb, b3, A, N);

    // ---- pool + MLP ----
    pool_mlp_kernel<<<NG, 256, 0, stream>>>(A, batch, fc1w, fc1b, fc2w, fc2b,
                                            (float*)d_out, N);
}

// Round 8
// 288.238 us; speedup vs baseline: 2.7267x; 1.1958x over previous
//
#include <hip/hip_runtime.h>
#include <hip/hip_bf16.h>
#include <cstdint>
#include <cstddef>

#define GAT_H 8
#define KBMAX 256          // max buckets (N <= 65536, bucket = dst >> 8)
#define BCAP  6144         // max edges per bucket staged in LDS (mean ~4350 here)

// fp32 -> bf16 with round-to-nearest-even, as raw ushort bits
__device__ __forceinline__ unsigned bf16r(float x) {
    const unsigned u = __float_as_uint(x);
    return (u + 0x7fffu + ((u >> 16) & 1u)) >> 16;
}
#define B2F_LO(u) __uint_as_float((u) << 16)
#define B2F_HI(u) __uint_as_float((u) & 0xffff0000u)

// ======================= bucketed CSR build (once per call) =======================
// Edges (incl. self-loops) are partitioned into 256-dst buckets; each bucket's CSR
// segment is built entirely in LDS by one block -> all HBM writes dense & exclusive.

__global__ __launch_bounds__(256) void bkt_count(const int* __restrict__ ei,
                                                 int* __restrict__ bcnt,
                                                 int nE, int nN, int kb) {
    __shared__ int lh[KBMAX];
    const int tid = threadIdx.x;
    for (int i = tid; i < kb; i += 256) lh[i] = 0;
    __syncthreads();
    const int ET = nE + nN;
    for (int e = blockIdx.x * 256 + tid; e < ET; e += gridDim.x * 256) {
        const int dst = (e < nE) ? ei[nE + e] : (e - nE);
        atomicAdd(&lh[dst >> 8], 1);
    }
    __syncthreads();
    for (int i = tid; i < kb; i += 256)
        if (lh[i]) atomicAdd(&bcnt[i], lh[i]);
}

__global__ __launch_bounds__(256) void bkt_scan(const int* __restrict__ bcnt,
                                                int* __restrict__ bbase,
                                                int* __restrict__ bwoff, int kb) {
    __shared__ int wt[4];
    const int tid = threadIdx.x, lane = tid & 63, wid = tid >> 6;
    const int v = (tid < kb) ? bcnt[tid] : 0;
    int incl = v;
    #pragma unroll
    for (int d = 1; d < 64; d <<= 1) {
        const int t = __shfl_up(incl, d, 64);
        if (lane >= d) incl += t;
    }
    if (lane == 63) wt[wid] = incl;
    __syncthreads();
    int add = 0;
    #pragma unroll
    for (int w = 0; w < 4; ++w) if (w < wid) add += wt[w];
    incl += add;
    if (tid < kb) {
        bbase[tid] = incl - v;
        bwoff[tid] = incl - v;
        if (tid == kb - 1) bbase[kb] = incl;
    }
}

// pack (dst,src) u16 pair; per-block per-bucket contiguous runs in staging
__global__ __launch_bounds__(256) void bkt_scatter(const int* __restrict__ ei,
                                                   int* __restrict__ bwoff,
                                                   unsigned* __restrict__ staging,
                                                   int nE, int nN, int kb) {
    __shared__ int cnt[KBMAX];
    __shared__ int gb[KBMAX];
    const int tid = threadIdx.x;
    const int base = blockIdx.x * 2048;
    for (int i = tid; i < kb; i += 256) cnt[i] = 0;
    __syncthreads();
    const int ET = nE + nN;
    unsigned pk[8]; int bb[8], lr[8];
    #pragma unroll
    for (int k = 0; k < 8; ++k) {
        const int e = base + k * 256 + tid;
        bb[k] = -1;
        if (e < ET) {
            int src, dst;
            if (e < nE) { src = ei[e]; dst = ei[nE + e]; }
            else        { src = dst = e - nE; }
            pk[k] = ((unsigned)dst << 16) | (unsigned)src;
            bb[k] = dst >> 8;
            lr[k] = atomicAdd(&cnt[bb[k]], 1);
        }
    }
    __syncthreads();
    for (int i = tid; i < kb; i += 256)
        gb[i] = cnt[i] ? atomicAdd(&bwoff[i], cnt[i]) : 0;
    __syncthreads();
    #pragma unroll
    for (int k = 0; k < 8; ++k)
        if (bb[k] >= 0) staging[gb[bb[k]] + lr[k]] = pk[k];
}

// one block per bucket: local hist -> scan -> rowptr, in-LDS scatter, dense write-out
__global__ __launch_bounds__(256) void bkt_build(const unsigned* __restrict__ staging,
                                                 const int* __restrict__ bbase,
                                                 int* __restrict__ rowptr,
                                                 int* __restrict__ esrc, int N) {
    __shared__ int hist[257];
    __shared__ int run[256];
    __shared__ int wt[4];
    __shared__ int outv[BCAP];
    const int b = blockIdx.x;
    const int lo = bbase[b], hi = bbase[b + 1];
    const int d0 = b << 8;
    const int nd = min(256, N - d0);
    const int tid = threadIdx.x, lane = tid & 63, wid = tid >> 6;

    hist[tid + 1] = 0;
    if (tid == 0) hist[0] = 0;
    run[tid] = 0;
    __syncthreads();
    for (int i = lo + tid; i < hi; i += 256) {
        const int dl = (int)(staging[i] >> 16) - d0;
        atomicAdd(&hist[dl + 1], 1);
    }
    __syncthreads();
    const int v = hist[tid + 1];
    __syncthreads();
    int incl = v;
    #pragma unroll
    for (int d = 1; d < 64; d <<= 1) {
        const int t = __shfl_up(incl, d, 64);
        if (lane >= d) incl += t;
    }
    if (lane == 63) wt[wid] = incl;
    __syncthreads();
    int add = 0;
    #pragma unroll
    for (int w = 0; w < 4; ++w) if (w < wid) add += wt[w];
    incl += add;
    hist[tid] = incl - v;                    // exclusive local offset for dst tid
    if (tid < nd) rowptr[d0 + tid + 1] = lo + incl;
    if (b == 0 && tid == 0) rowptr[0] = 0;
    __syncthreads();
    for (int i = lo + tid; i < hi; i += 256) {
        const unsigned p = staging[i];
        const int dl = (int)(p >> 16) - d0;
        const int pos = hist[dl] + atomicAdd(&run[dl], 1);
        const int sv = (int)(p & 0xffffu);
        if (pos < BCAP) outv[pos] = sv;
        else            esrc[lo + pos] = sv;  // overflow fallback (never hit at this scale)
    }
    __syncthreads();
    const int cnt = hi - lo;
    const int lim = min(cnt, BCAP);
    for (int i = tid; i < lim; i += 256) esrc[lo + i] = outv[i];
}

// ======================= fused node matmul + attention logits + head max =======================

template<int D, int C, int KK, int F>
__global__ __launch_bounds__(256) void matmul_fused(
        const float* __restrict__ X, const float* __restrict__ W,
        const float* __restrict__ a_src, const float* __restrict__ a_dst,
        unsigned short* __restrict__ Hb,
        float* __restrict__ als, float* __restrict__ ald,
        float* __restrict__ Mh, int N) {
    constexpr int CG  = C / 8;
    constexpr int NGR = 256 / CG;
    constexpr int NPT = 64 / NGR;
    constexpr int XS  = KK + 4;
    __shared__ float xs[64][XS];
    __shared__ float wsh[KK][C];
    __shared__ float2 phl[64][GAT_H];
    __shared__ int bmax[GAT_H];

    const int n0 = blockIdx.x * 64;
    const int tid = threadIdx.x;
    const int cg = tid % CG, ngr = tid / CG;
    const int c0 = cg * 8;
    if (tid < GAT_H) bmax[tid] = 0;

    float acc[NPT][8];
    #pragma unroll
    for (int i = 0; i < NPT; ++i)
        #pragma unroll
        for (int j = 0; j < 8; ++j) acc[i][j] = 0.f;

    for (int k0 = 0; k0 < D; k0 += KK) {
        for (int t = tid; t < 64 * (KK / 4); t += 256) {
            const int row = t / (KK / 4), c4 = (t % (KK / 4)) * 4;
            const int n = n0 + row;
            float4 v = make_float4(0.f, 0.f, 0.f, 0.f);
            if (n < N) v = *reinterpret_cast<const float4*>(&X[(size_t)n * D + k0 + c4]);
            *reinterpret_cast<float4*>(&xs[row][c4]) = v;
        }
        for (int t = tid; t < KK * (C / 4); t += 256) {
            const int row = t / (C / 4), c4 = (t % (C / 4)) * 4;
            *reinterpret_cast<float4*>(&wsh[row][c4]) =
                *reinterpret_cast<const float4*>(&W[(size_t)(k0 + row) * C + c4]);
        }
        __syncthreads();

        #pragma unroll
        for (int k4 = 0; k4 < KK; k4 += 4) {
            float4 xv[NPT];
            #pragma unroll
            for (int i = 0; i < NPT; ++i)
                xv[i] = *reinterpret_cast<const float4*>(&xs[ngr * NPT + i][k4]);
            #pragma unroll
            for (int kk = 0; kk < 4; ++kk) {
                const float4 w0 = *reinterpret_cast<const float4*>(&wsh[k4 + kk][c0]);
                const float4 w1 = *reinterpret_cast<const float4*>(&wsh[k4 + kk][c0 + 4]);
                #pragma unroll
                for (int i = 0; i < NPT; ++i) {
                    const float xk = (kk == 0) ? xv[i].x : (kk == 1) ? xv[i].y
                                   : (kk == 2) ? xv[i].z : xv[i].w;
                    acc[i][0] += xk * w0.x; acc[i][1] += xk * w0.y;
                    acc[i][2] += xk * w0.z; acc[i][3] += xk * w0.w;
                    acc[i][4] += xk * w1.x; acc[i][5] += xk * w1.y;
                    acc[i][6] += xk * w1.z; acc[i][7] += xk * w1.w;
                }
            }
        }
        __syncthreads();
    }

    // ---- epilogue: bf16 store + fused logits ----
    const int h   = c0 / F;
    const int off = c0 % F;
    float asr[8], adr[8];
    #pragma unroll
    for (int q = 0; q < 8; ++q) {
        asr[q] = a_src[h * F + off + q];
        adr[q] = a_dst[h * F + off + q];
    }

    float ps[NPT], pd[NPT];
    #pragma unroll
    for (int i = 0; i < NPT; ++i) {
        float s = 0.f, d2 = 0.f;
        #pragma unroll
        for (int q = 0; q < 8; ++q) { s += acc[i][q] * asr[q]; d2 += acc[i][q] * adr[q]; }
        ps[i] = s; pd[i] = d2;
        const int n = n0 + ngr * NPT + i;
        if (n < N) {
            uint4 pk;
            pk.x = bf16r(acc[i][0]) | (bf16r(acc[i][1]) << 16);
            pk.y = bf16r(acc[i][2]) | (bf16r(acc[i][3]) << 16);
            pk.z = bf16r(acc[i][4]) | (bf16r(acc[i][5]) << 16);
            pk.w = bf16r(acc[i][6]) | (bf16r(acc[i][7]) << 16);
            *reinterpret_cast<uint4*>(&Hb[(size_t)n * C + c0]) = pk;
        }
    }

    if constexpr (F == 16) {
        if (cg & 1) {
            #pragma unroll
            for (int i = 0; i < NPT; ++i)
                phl[ngr * NPT + i][h] = make_float2(ps[i], pd[i]);
        }
        __syncthreads();
        if (!(cg & 1)) {
            #pragma unroll
            for (int i = 0; i < NPT; ++i) {
                const int nl = ngr * NPT + i;
                const int n = n0 + nl;
                const float al = ps[i] + phl[nl][h].x;
                const float ad = pd[i] + phl[nl][h].y;
                if (n < N) {
                    als[(size_t)n * GAT_H + h] = al;
                    ald[(size_t)n * GAT_H + h] = ad;
                    if (al > 0.f) atomicMax(&bmax[h], __float_as_int(al));
                }
            }
        }
    } else {
        #pragma unroll
        for (int i = 0; i < NPT; ++i) {
            const int n = n0 + ngr * NPT + i;
            if (n < N) {
                als[(size_t)n * GAT_H + h] = ps[i];
                ald[(size_t)n * GAT_H + h] = pd[i];
                if (ps[i] > 0.f) atomicMax(&bmax[h], __float_as_int(ps[i]));
            }
        }
    }
    __syncthreads();
    if (tid < GAT_H) {
        const int v = bmax[tid];
        if (v > 0) atomicMax((int*)&Mh[tid], v);
    }
}

// ======================= fused gather: branch-free softmax + bf16 weighted sum + ELU =======================

template<int F>
__global__ void gat_gather(const int* __restrict__ rowptr, const int* __restrict__ esrc,
                           const float* __restrict__ als, const float* __restrict__ ald,
                           const float* __restrict__ Mh,
                           const unsigned short* __restrict__ Hb, const float* __restrict__ b,
                           float* __restrict__ out, int N) {
    const int t = blockIdx.x * blockDim.x + threadIdx.x;
    if (t >= N * GAT_H) return;
    const int dst = t >> 3, h = t & 7;
    const int beg = rowptr[dst], end = rowptr[dst + 1];
    const float adh = ald[t];
    float bnd = Mh[h] + adh;
    bnd = bnd > 0.f ? bnd : 0.2f * bnd;

    constexpr int NW = F / 2;
    float s = 0.f;
    float acc[F];
    #pragma unroll
    for (int j = 0; j < F; ++j) acc[j] = 0.f;

    int src0 = esrc[beg];
    float al0 = als[src0 * GAT_H + h];
    for (int i = beg; i < end; ++i) {
        union { uint4 q[NW / 4]; unsigned w[NW]; } v;
        const uint4* hq = reinterpret_cast<const uint4*>(Hb + ((size_t)src0 * GAT_H + h) * F);
        #pragma unroll
        for (int j = 0; j < NW / 4; ++j) v.q[j] = hq[j];

        const int inext = (i + 1 < end) ? i + 1 : i;
        const int src1 = esrc[inext];
        const float al1 = als[src1 * GAT_H + h];

        float x = al0 + adh;
        x = x > 0.f ? x : 0.2f * x;
        const float p = __expf(x - bnd);
        s += p;
        #pragma unroll
        for (int j = 0; j < NW; ++j) {
            acc[2 * j]     += p * B2F_LO(v.w[j]);
            acc[2 * j + 1] += p * B2F_HI(v.w[j]);
        }
        src0 = src1; al0 = al1;
    }

    const float inv = 1.f / s;
    #pragma unroll
    for (int j = 0; j < F / 4; ++j) {
        float vv[4];
        #pragma unroll
        for (int q = 0; q < 4; ++q) {
            const float val = acc[4 * j + q] * inv + b[h * F + 4 * j + q];
            vv[q] = val > 0.f ? val : expm1f(val);
        }
        *reinterpret_cast<float4*>(&out[((size_t)dst * GAT_H + h) * F + 4 * j]) =
            make_float4(vv[0], vv[1], vv[2], vv[3]);
    }
}

// ======================= pooling + MLP, fused =======================

__global__ __launch_bounds__(256) void pool_mlp_kernel(
        const float* __restrict__ A, const int* __restrict__ batch,
        const float* __restrict__ fc1w, const float* __restrict__ fc1b,
        const float* __restrict__ fc2w, const float* __restrict__ fc2b,
        float* __restrict__ out, int N) {
    const int g = blockIdx.x;
    int lo, hi;
    {
        int l = 0, h2 = N;
        while (l < h2) { const int mid = (l + h2) >> 1; if (batch[mid] < g) l = mid + 1; else h2 = mid; }
        lo = l;
        h2 = N;
        while (l < h2) { const int mid = (l + h2) >> 1; if (batch[mid] < g + 1) l = mid + 1; else h2 = mid; }
        hi = l;
    }
    __shared__ float4 part[8][32];
    __shared__ float pl[128];
    __shared__ float red2[32];
    const int tid = threadIdx.x;
    const int c4 = (tid & 31) * 4, r = tid >> 5;
    float4 acc = make_float4(0.f, 0.f, 0.f, 0.f);
    for (int n = lo + r; n < hi; n += 8) {
        const float4 v = *reinterpret_cast<const float4*>(&A[(size_t)n * 128 + c4]);
        acc.x += v.x; acc.y += v.y; acc.z += v.z; acc.w += v.w;
    }
    part[r][tid & 31] = acc;
    __syncthreads();
    if (tid < 32) {
        float4 s = part[0][tid];
        #pragma unroll
        for (int rr = 1; rr < 8; ++rr) {
            const float4 v = part[rr][tid];
            s.x += v.x; s.y += v.y; s.z += v.z; s.w += v.w;
        }
        const float invc = 1.f / fmaxf((float)(hi - lo), 1.f);
        pl[tid * 4]     = s.x * invc;
        pl[tid * 4 + 1] = s.y * invc;
        pl[tid * 4 + 2] = s.z * invc;
        pl[tid * 4 + 3] = s.w * invc;
    }
    __syncthreads();
    if (tid < 32) {
        float a = fc1b[tid];
        for (int k = 0; k < 128; ++k) a += pl[k] * fc1w[k * 32 + tid];
        a = fmaxf(a, 0.f);
        red2[tid] = a * fc2w[tid];
    }
    __syncthreads();
    if (tid == 0) {
        float sum = fc2b[0];
        for (int k = 0; k < 32; ++k) sum += red2[k];
        out[g] = sum;
    }
}

// ======================= launch =======================

extern "C" void kernel_launch(void* const* d_in, const int* in_sizes, int n_in,
                              void* d_out, int out_size, void* d_ws, size_t ws_size,
                              hipStream_t stream) {
    const float* x     = (const float*)d_in[0];
    const int*   ei    = (const int*)  d_in[1];
    const int*   batch = (const int*)  d_in[2];
    const float* W1 = (const float*)d_in[3],  *as1 = (const float*)d_in[4],
               *ad1 = (const float*)d_in[5],  *b1  = (const float*)d_in[6];
    const float* W2 = (const float*)d_in[7],  *as2 = (const float*)d_in[8],
               *ad2 = (const float*)d_in[9],  *b2  = (const float*)d_in[10];
    const float* W3 = (const float*)d_in[11], *as3 = (const float*)d_in[12],
               *ad3 = (const float*)d_in[13], *b3  = (const float*)d_in[14];
    const float* fc1w = (const float*)d_in[15], *fc1b = (const float*)d_in[16];
    const float* fc2w = (const float*)d_in[17], *fc2b = (const float*)d_in[18];

    const int N  = in_sizes[0] / 16;     // 50000
    const int NE = in_sizes[1] / 2;      // 800000
    const int NG = out_size;             // 256
    const int ET = NE + N;               // edges incl. self-loops
    const int KB = (N + 255) >> 8;       // buckets of 256 dsts

    // workspace layout (16B alignment maintained)
    float* ws = (float*)d_ws;
    size_t off = 0;
    float* A    = ws + off; off += (size_t)N * 128;
    unsigned short* Hb = (unsigned short*)(ws + off); off += (size_t)N * 64;  // bf16 h
    float* als  = ws + off; off += (size_t)N * GAT_H;
    float* ald  = ws + off; off += (size_t)N * GAT_H;
    float* Mh   = ws + off; off += 3 * GAT_H;
    int* rowptr = (int*)(ws + off); off += N + 1;
    int* esrc   = (int*)(ws + off); off += ET;
    unsigned* staging = (unsigned*)(ws + off); off += ET;
    int* bcnt   = (int*)(ws + off); off += KBMAX;
    int* bbase  = (int*)(ws + off); off += KBMAX + 1;
    int* bwoff  = (int*)(ws + off); off += KBMAX;

    // ---- bucketed CSR build (graph identical for all 3 layers) ----
    hipMemsetAsync(bcnt, 0, KBMAX * sizeof(int), stream);
    hipMemsetAsync(Mh, 0, 3 * GAT_H * sizeof(float), stream);
    bkt_count<<<512, 256, 0, stream>>>(ei, bcnt, NE, N, KB);
    bkt_scan<<<1, 256, 0, stream>>>(bcnt, bbase, bwoff, KB);
    bkt_scatter<<<(ET + 2047) / 2048, 256, 0, stream>>>(ei, bwoff, staging, NE, N, KB);
    bkt_build<<<KB, 256, 0, stream>>>(staging, bbase, rowptr, esrc, N);

    const int NH = N * GAT_H;
    const int NHB = (NH + 255) / 256;
    const int NB = (N + 63) / 64;

    // ---- layer 1: 16 -> 8x8 ----
    matmul_fused<16, 64, 16, 8><<<NB, 256, 0, stream>>>(x, W1, as1, ad1, Hb, als, ald, Mh, N);
    gat_gather<8><<<NHB, 256, 0, stream>>>(rowptr, esrc, als, ald, Mh, Hb, b1, A, N);

    // ---- layer 2: 64 -> 8x16 ----
    matmul_fused<64, 128, 32, 16><<<NB, 256, 0, stream>>>(A, W2, as2, ad2, Hb, als, ald, Mh + GAT_H, N);
    gat_gather<16><<<NHB, 256, 0, stream>>>(rowptr, esrc, als, ald, Mh + GAT_H, Hb, b2, A, N);

    // ---- layer 3: 128 -> 8x16 ----
    matmul_fused<128, 128, 32, 16><<<NB, 256, 0, stream>>>(A, W3, as3, ad3, Hb, als, ald, Mh + 2 * GAT_H, N);
    gat_gather<16><<<NHB, 256, 0, stream>>>(rowptr, esrc, als, ald, Mh + 2 * GAT_H, Hb, b3, A, N);

    // ---- pool + MLP ----
    pool_mlp_kernel<<<NG, 256, 0, stream>>>(A, batch, fc1w, fc1b, fc2w, fc2b,
                                            (float*)d_out, N);
}

// Round 9
// 285.886 us; speedup vs baseline: 2.7492x; 1.0082x over previous
//
#include <hip/hip_runtime.h>
#include <hip/hip_bf16.h>
#include <cstdint>
#include <cstddef>

#define GAT_H 8
#define KBMAX 256          // max buckets (N <= 65536, bucket = dst >> 8)
#define BCAP  6144         // max edges per bucket staged in LDS (mean ~4350 here)

// fp32 -> bf16 with round-to-nearest-even, as raw ushort bits
__device__ __forceinline__ unsigned bf16r(float x) {
    const unsigned u = __float_as_uint(x);
    return (u + 0x7fffu + ((u >> 16) & 1u)) >> 16;
}
#define B2F_LO(u) __uint_as_float((u) << 16)
#define B2F_HI(u) __uint_as_float((u) & 0xffff0000u)

// ======================= bucketed CSR build (once per call) =======================

__global__ __launch_bounds__(256) void bkt_count(const int* __restrict__ ei,
                                                 int* __restrict__ bcnt,
                                                 int nE, int nN, int kb) {
    __shared__ int lh[KBMAX];
    const int tid = threadIdx.x;
    for (int i = tid; i < kb; i += 256) lh[i] = 0;
    __syncthreads();
    const int ET = nE + nN;
    for (int e = blockIdx.x * 256 + tid; e < ET; e += gridDim.x * 256) {
        const int dst = (e < nE) ? ei[nE + e] : (e - nE);
        atomicAdd(&lh[dst >> 8], 1);
    }
    __syncthreads();
    for (int i = tid; i < kb; i += 256)
        if (lh[i]) atomicAdd(&bcnt[i], lh[i]);
}

__global__ __launch_bounds__(256) void bkt_scan(const int* __restrict__ bcnt,
                                                int* __restrict__ bbase,
                                                int* __restrict__ bwoff, int kb) {
    __shared__ int wt[4];
    const int tid = threadIdx.x, lane = tid & 63, wid = tid >> 6;
    const int v = (tid < kb) ? bcnt[tid] : 0;
    int incl = v;
    #pragma unroll
    for (int d = 1; d < 64; d <<= 1) {
        const int t = __shfl_up(incl, d, 64);
        if (lane >= d) incl += t;
    }
    if (lane == 63) wt[wid] = incl;
    __syncthreads();
    int add = 0;
    #pragma unroll
    for (int w = 0; w < 4; ++w) if (w < wid) add += wt[w];
    incl += add;
    if (tid < kb) {
        bbase[tid] = incl - v;
        bwoff[tid] = incl - v;
        if (tid == kb - 1) bbase[kb] = incl;
    }
}

__global__ __launch_bounds__(256) void bkt_scatter(const int* __restrict__ ei,
                                                   int* __restrict__ bwoff,
                                                   unsigned* __restrict__ staging,
                                                   int nE, int nN, int kb) {
    __shared__ int cnt[KBMAX];
    __shared__ int gb[KBMAX];
    const int tid = threadIdx.x;
    const int base = blockIdx.x * 2048;
    for (int i = tid; i < kb; i += 256) cnt[i] = 0;
    __syncthreads();
    const int ET = nE + nN;
    unsigned pk[8]; int bb[8], lr[8];
    #pragma unroll
    for (int k = 0; k < 8; ++k) {
        const int e = base + k * 256 + tid;
        bb[k] = -1;
        if (e < ET) {
            int src, dst;
            if (e < nE) { src = ei[e]; dst = ei[nE + e]; }
            else        { src = dst = e - nE; }
            pk[k] = ((unsigned)dst << 16) | (unsigned)src;
            bb[k] = dst >> 8;
            lr[k] = atomicAdd(&cnt[bb[k]], 1);
        }
    }
    __syncthreads();
    for (int i = tid; i < kb; i += 256)
        gb[i] = cnt[i] ? atomicAdd(&bwoff[i], cnt[i]) : 0;
    __syncthreads();
    #pragma unroll
    for (int k = 0; k < 8; ++k)
        if (bb[k] >= 0) staging[gb[bb[k]] + lr[k]] = pk[k];
}

__global__ __launch_bounds__(256) void bkt_build(const unsigned* __restrict__ staging,
                                                 const int* __restrict__ bbase,
                                                 int* __restrict__ rowptr,
                                                 int* __restrict__ esrc, int N) {
    __shared__ int hist[257];
    __shared__ int run[256];
    __shared__ int wt[4];
    __shared__ int outv[BCAP];
    const int b = blockIdx.x;
    const int lo = bbase[b], hi = bbase[b + 1];
    const int d0 = b << 8;
    const int nd = min(256, N - d0);
    const int tid = threadIdx.x, lane = tid & 63, wid = tid >> 6;

    hist[tid + 1] = 0;
    if (tid == 0) hist[0] = 0;
    run[tid] = 0;
    __syncthreads();
    for (int i = lo + tid; i < hi; i += 256) {
        const int dl = (int)(staging[i] >> 16) - d0;
        atomicAdd(&hist[dl + 1], 1);
    }
    __syncthreads();
    const int v = hist[tid + 1];
    __syncthreads();
    int incl = v;
    #pragma unroll
    for (int d = 1; d < 64; d <<= 1) {
        const int t = __shfl_up(incl, d, 64);
        if (lane >= d) incl += t;
    }
    if (lane == 63) wt[wid] = incl;
    __syncthreads();
    int add = 0;
    #pragma unroll
    for (int w = 0; w < 4; ++w) if (w < wid) add += wt[w];
    incl += add;
    hist[tid] = incl - v;
    if (tid < nd) rowptr[d0 + tid + 1] = lo + incl;
    if (b == 0 && tid == 0) rowptr[0] = 0;
    __syncthreads();
    for (int i = lo + tid; i < hi; i += 256) {
        const unsigned p = staging[i];
        const int dl = (int)(p >> 16) - d0;
        const int pos = hist[dl] + atomicAdd(&run[dl], 1);
        const int sv = (int)(p & 0xffffu);
        if (pos < BCAP) outv[pos] = sv;
        else            esrc[lo + pos] = sv;
    }
    __syncthreads();
    const int cnt = hi - lo;
    const int lim = min(cnt, BCAP);
    for (int i = tid; i < lim; i += 256) esrc[lo + i] = outv[i];
}

// ======================= fused node matmul + attention logits + head max =======================

template<int D, int C, int KK, int F>
__global__ __launch_bounds__(256) void matmul_fused(
        const float* __restrict__ X, const float* __restrict__ W,
        const float* __restrict__ a_src, const float* __restrict__ a_dst,
        unsigned short* __restrict__ Hb,
        float* __restrict__ als, float* __restrict__ ald,
        float* __restrict__ Mh, int N) {
    constexpr int CG  = C / 8;
    constexpr int NGR = 256 / CG;
    constexpr int NPT = 64 / NGR;
    constexpr int XS  = KK + 4;
    __shared__ float xs[64][XS];
    __shared__ float wsh[KK][C];
    __shared__ float2 phl[64][GAT_H];
    __shared__ int bmax[GAT_H];

    const int n0 = blockIdx.x * 64;
    const int tid = threadIdx.x;
    const int cg = tid % CG, ngr = tid / CG;
    const int c0 = cg * 8;
    if (tid < GAT_H) bmax[tid] = 0;

    float acc[NPT][8];
    #pragma unroll
    for (int i = 0; i < NPT; ++i)
        #pragma unroll
        for (int j = 0; j < 8; ++j) acc[i][j] = 0.f;

    for (int k0 = 0; k0 < D; k0 += KK) {
        for (int t = tid; t < 64 * (KK / 4); t += 256) {
            const int row = t / (KK / 4), c4 = (t % (KK / 4)) * 4;
            const int n = n0 + row;
            float4 v = make_float4(0.f, 0.f, 0.f, 0.f);
            if (n < N) v = *reinterpret_cast<const float4*>(&X[(size_t)n * D + k0 + c4]);
            *reinterpret_cast<float4*>(&xs[row][c4]) = v;
        }
        for (int t = tid; t < KK * (C / 4); t += 256) {
            const int row = t / (C / 4), c4 = (t % (C / 4)) * 4;
            *reinterpret_cast<float4*>(&wsh[row][c4]) =
                *reinterpret_cast<const float4*>(&W[(size_t)(k0 + row) * C + c4]);
        }
        __syncthreads();

        #pragma unroll
        for (int k4 = 0; k4 < KK; k4 += 4) {
            float4 xv[NPT];
            #pragma unroll
            for (int i = 0; i < NPT; ++i)
                xv[i] = *reinterpret_cast<const float4*>(&xs[ngr * NPT + i][k4]);
            #pragma unroll
            for (int kk = 0; kk < 4; ++kk) {
                const float4 w0 = *reinterpret_cast<const float4*>(&wsh[k4 + kk][c0]);
                const float4 w1 = *reinterpret_cast<const float4*>(&wsh[k4 + kk][c0 + 4]);
                #pragma unroll
                for (int i = 0; i < NPT; ++i) {
                    const float xk = (kk == 0) ? xv[i].x : (kk == 1) ? xv[i].y
                                   : (kk == 2) ? xv[i].z : xv[i].w;
                    acc[i][0] += xk * w0.x; acc[i][1] += xk * w0.y;
                    acc[i][2] += xk * w0.z; acc[i][3] += xk * w0.w;
                    acc[i][4] += xk * w1.x; acc[i][5] += xk * w1.y;
                    acc[i][6] += xk * w1.z; acc[i][7] += xk * w1.w;
                }
            }
        }
        __syncthreads();
    }

    // ---- epilogue: bf16 store + fused logits ----
    const int h   = c0 / F;
    const int off = c0 % F;
    float asr[8], adr[8];
    #pragma unroll
    for (int q = 0; q < 8; ++q) {
        asr[q] = a_src[h * F + off + q];
        adr[q] = a_dst[h * F + off + q];
    }

    float ps[NPT], pd[NPT];
    #pragma unroll
    for (int i = 0; i < NPT; ++i) {
        float s = 0.f, d2 = 0.f;
        #pragma unroll
        for (int q = 0; q < 8; ++q) { s += acc[i][q] * asr[q]; d2 += acc[i][q] * adr[q]; }
        ps[i] = s; pd[i] = d2;
        const int n = n0 + ngr * NPT + i;
        if (n < N) {
            uint4 pk;
            pk.x = bf16r(acc[i][0]) | (bf16r(acc[i][1]) << 16);
            pk.y = bf16r(acc[i][2]) | (bf16r(acc[i][3]) << 16);
            pk.z = bf16r(acc[i][4]) | (bf16r(acc[i][5]) << 16);
            pk.w = bf16r(acc[i][6]) | (bf16r(acc[i][7]) << 16);
            *reinterpret_cast<uint4*>(&Hb[(size_t)n * C + c0]) = pk;
        }
    }

    if constexpr (F == 16) {
        if (cg & 1) {
            #pragma unroll
            for (int i = 0; i < NPT; ++i)
                phl[ngr * NPT + i][h] = make_float2(ps[i], pd[i]);
        }
        __syncthreads();
        if (!(cg & 1)) {
            #pragma unroll
            for (int i = 0; i < NPT; ++i) {
                const int nl = ngr * NPT + i;
                const int n = n0 + nl;
                const float al = ps[i] + phl[nl][h].x;
                const float ad = pd[i] + phl[nl][h].y;
                if (n < N) {
                    als[(size_t)n * GAT_H + h] = al;
                    ald[(size_t)n * GAT_H + h] = ad;
                    if (al > 0.f) atomicMax(&bmax[h], __float_as_int(al));
                }
            }
        }
    } else {
        #pragma unroll
        for (int i = 0; i < NPT; ++i) {
            const int n = n0 + ngr * NPT + i;
            if (n < N) {
                als[(size_t)n * GAT_H + h] = ps[i];
                ald[(size_t)n * GAT_H + h] = pd[i];
                if (ps[i] > 0.f) atomicMax(&bmax[h], __float_as_int(ps[i]));
            }
        }
    }
    __syncthreads();
    if (tid < GAT_H) {
        const int v = bmax[tid];
        if (v > 0) atomicMax((int*)&Mh[tid], v);
    }
}

// ======================= fused gather: 2-edge-unrolled softmax + bf16 weighted sum + ELU =======================

template<int F>
__global__ void gat_gather(const int* __restrict__ rowptr, const int* __restrict__ esrc,
                           const float* __restrict__ als, const float* __restrict__ ald,
                           const float* __restrict__ Mh,
                           const unsigned short* __restrict__ Hb, const float* __restrict__ b,
                           float* __restrict__ out, int N) {
    const int t = blockIdx.x * blockDim.x + threadIdx.x;
    if (t >= N * GAT_H) return;
    const int dst = t >> 3, h = t & 7;
    const int beg = rowptr[dst], end = rowptr[dst + 1];
    const float adh = ald[t];
    float bnd = Mh[h] + adh;
    bnd = bnd > 0.f ? bnd : 0.2f * bnd;          // leaky(Mh+adh) >= segment max logit

    constexpr int NW = F / 2;                    // u32 words per head-slice
    float s = 0.f;
    float acc[F];
    #pragma unroll
    for (int j = 0; j < F; ++j) acc[j] = 0.f;

    int i = beg;
    // 2 edges per iteration: 6 independent loads in flight before any use
    for (; i + 1 < end; i += 2) {
        const int sa = esrc[i], sb = esrc[i + 1];
        const float ala = als[sa * GAT_H + h];
        const float alb = als[sb * GAT_H + h];
        union { uint4 q[NW / 4]; unsigned w[NW]; } va, vb;
        const uint4* ha = reinterpret_cast<const uint4*>(Hb + ((size_t)sa * GAT_H + h) * F);
        const uint4* hb2 = reinterpret_cast<const uint4*>(Hb + ((size_t)sb * GAT_H + h) * F);
        #pragma unroll
        for (int j = 0; j < NW / 4; ++j) { va.q[j] = ha[j]; vb.q[j] = hb2[j]; }

        float xa = ala + adh; xa = xa > 0.f ? xa : 0.2f * xa;
        float xb = alb + adh; xb = xb > 0.f ? xb : 0.2f * xb;
        const float pa = __expf(xa - bnd);
        const float pb = __expf(xb - bnd);
        s += pa + pb;
        #pragma unroll
        for (int j = 0; j < NW; ++j) {
            acc[2 * j]     += pa * B2F_LO(va.w[j]) + pb * B2F_LO(vb.w[j]);
            acc[2 * j + 1] += pa * B2F_HI(va.w[j]) + pb * B2F_HI(vb.w[j]);
        }
    }
    if (i < end) {                                // odd tail
        const int sa = esrc[i];
        const float ala = als[sa * GAT_H + h];
        union { uint4 q[NW / 4]; unsigned w[NW]; } va;
        const uint4* ha = reinterpret_cast<const uint4*>(Hb + ((size_t)sa * GAT_H + h) * F);
        #pragma unroll
        for (int j = 0; j < NW / 4; ++j) va.q[j] = ha[j];
        float xa = ala + adh; xa = xa > 0.f ? xa : 0.2f * xa;
        const float pa = __expf(xa - bnd);
        s += pa;
        #pragma unroll
        for (int j = 0; j < NW; ++j) {
            acc[2 * j]     += pa * B2F_LO(va.w[j]);
            acc[2 * j + 1] += pa * B2F_HI(va.w[j]);
        }
    }

    const float inv = 1.f / s;                   // s > 0 (self-loop term)
    #pragma unroll
    for (int j = 0; j < F / 4; ++j) {
        float vv[4];
        #pragma unroll
        for (int q = 0; q < 4; ++q) {
            const float val = acc[4 * j + q] * inv + b[h * F + 4 * j + q];
            vv[q] = val > 0.f ? val : expm1f(val);   // ELU
        }
        *reinterpret_cast<float4*>(&out[((size_t)dst * GAT_H + h) * F + 4 * j]) =
            make_float4(vv[0], vv[1], vv[2], vv[3]);
    }
}

// ======================= pooling + MLP, fused =======================

__global__ __launch_bounds__(256) void pool_mlp_kernel(
        const float* __restrict__ A, const int* __restrict__ batch,
        const float* __restrict__ fc1w, const float* __restrict__ fc1b,
        const float* __restrict__ fc2w, const float* __restrict__ fc2b,
        float* __restrict__ out, int N) {
    const int g = blockIdx.x;
    int lo, hi;
    {
        int l = 0, h2 = N;
        while (l < h2) { const int mid = (l + h2) >> 1; if (batch[mid] < g) l = mid + 1; else h2 = mid; }
        lo = l;
        h2 = N;
        while (l < h2) { const int mid = (l + h2) >> 1; if (batch[mid] < g + 1) l = mid + 1; else h2 = mid; }
        hi = l;
    }
    __shared__ float4 part[8][32];
    __shared__ float pl[128];
    __shared__ float red2[32];
    const int tid = threadIdx.x;
    const int c4 = (tid & 31) * 4, r = tid >> 5;
    float4 acc = make_float4(0.f, 0.f, 0.f, 0.f);
    for (int n = lo + r; n < hi; n += 8) {
        const float4 v = *reinterpret_cast<const float4*>(&A[(size_t)n * 128 + c4]);
        acc.x += v.x; acc.y += v.y; acc.z += v.z; acc.w += v.w;
    }
    part[r][tid & 31] = acc;
    __syncthreads();
    if (tid < 32) {
        float4 s = part[0][tid];
        #pragma unroll
        for (int rr = 1; rr < 8; ++rr) {
            const float4 v = part[rr][tid];
            s.x += v.x; s.y += v.y; s.z += v.z; s.w += v.w;
        }
        const float invc = 1.f / fmaxf((float)(hi - lo), 1.f);
        pl[tid * 4]     = s.x * invc;
        pl[tid * 4 + 1] = s.y * invc;
        pl[tid * 4 + 2] = s.z * invc;
        pl[tid * 4 + 3] = s.w * invc;
    }
    __syncthreads();
    if (tid < 32) {
        float a = fc1b[tid];
        for (int k = 0; k < 128; ++k) a += pl[k] * fc1w[k * 32 + tid];
        a = fmaxf(a, 0.f);
        red2[tid] = a * fc2w[tid];
    }
    __syncthreads();
    if (tid == 0) {
        float sum = fc2b[0];
        for (int k = 0; k < 32; ++k) sum += red2[k];
        out[g] = sum;
    }
}

// ======================= launch =======================

extern "C" void kernel_launch(void* const* d_in, const int* in_sizes, int n_in,
                              void* d_out, int out_size, void* d_ws, size_t ws_size,
                              hipStream_t stream) {
    const float* x     = (const float*)d_in[0];
    const int*   ei    = (const int*)  d_in[1];
    const int*   batch = (const int*)  d_in[2];
    const float* W1 = (const float*)d_in[3],  *as1 = (const float*)d_in[4],
               *ad1 = (const float*)d_in[5],  *b1  = (const float*)d_in[6];
    const float* W2 = (const float*)d_in[7],  *as2 = (const float*)d_in[8],
               *ad2 = (const float*)d_in[9],  *b2  = (const float*)d_in[10];
    const float* W3 = (const float*)d_in[11], *as3 = (const float*)d_in[12],
               *ad3 = (const float*)d_in[13], *b3  = (const float*)d_in[14];
    const float* fc1w = (const float*)d_in[15], *fc1b = (const float*)d_in[16];
    const float* fc2w = (const float*)d_in[17], *fc2b = (const float*)d_in[18];

    const int N  = in_sizes[0] / 16;     // 50000
    const int NE = in_sizes[1] / 2;      // 800000
    const int NG = out_size;             // 256
    const int ET = NE + N;               // edges incl. self-loops
    const int KB = (N + 255) >> 8;       // buckets of 256 dsts

    // workspace layout (16B alignment maintained)
    float* ws = (float*)d_ws;
    size_t off = 0;
    float* A    = ws + off; off += (size_t)N * 128;
    unsigned short* Hb = (unsigned short*)(ws + off); off += (size_t)N * 64;  // bf16 h
    float* als  = ws + off; off += (size_t)N * GAT_H;
    float* ald  = ws + off; off += (size_t)N * GAT_H;
    float* Mh   = ws + off; off += 3 * GAT_H;
    int* rowptr = (int*)(ws + off); off += N + 1;
    int* esrc   = (int*)(ws + off); off += ET;
    unsigned* staging = (unsigned*)(ws + off); off += ET;
    int* bcnt   = (int*)(ws + off); off += KBMAX;
    int* bbase  = (int*)(ws + off); off += KBMAX + 1;
    int* bwoff  = (int*)(ws + off); off += KBMAX;

    // ---- bucketed CSR build (graph identical for all 3 layers) ----
    hipMemsetAsync(bcnt, 0, KBMAX * sizeof(int), stream);
    hipMemsetAsync(Mh, 0, 3 * GAT_H * sizeof(float), stream);
    bkt_count<<<512, 256, 0, stream>>>(ei, bcnt, NE, N, KB);
    bkt_scan<<<1, 256, 0, stream>>>(bcnt, bbase, bwoff, KB);
    bkt_scatter<<<(ET + 2047) / 2048, 256, 0, stream>>>(ei, bwoff, staging, NE, N, KB);
    bkt_build<<<KB, 256, 0, stream>>>(staging, bbase, rowptr, esrc, N);

    const int NH = N * GAT_H;
    const int NHB = (NH + 255) / 256;
    const int NB = (N + 63) / 64;

    // ---- layer 1: 16 -> 8x8 ----
    matmul_fused<16, 64, 16, 8><<<NB, 256, 0, stream>>>(x, W1, as1, ad1, Hb, als, ald, Mh, N);
    gat_gather<8><<<NHB, 256, 0, stream>>>(rowptr, esrc, als, ald, Mh, Hb, b1, A, N);

    // ---- layer 2: 64 -> 8x16 ----
    matmul_fused<64, 128, 32, 16><<<NB, 256, 0, stream>>>(A, W2, as2, ad2, Hb, als, ald, Mh + GAT_H, N);
    gat_gather<16><<<NHB, 256, 0, stream>>>(rowptr, esrc, als, ald, Mh + GAT_H, Hb, b2, A, N);

    // ---- layer 3: 128 -> 8x16 ----
    matmul_fused<128, 128, 32, 16><<<NB, 256, 0, stream>>>(A, W3, as3, ad3, Hb, als, ald, Mh + 2 * GAT_H, N);
    gat_gather<16><<<NHB, 256, 0, stream>>>(rowptr, esrc, als, ald, Mh + 2 * GAT_H, Hb, b3, A, N);

    // ---- pool + MLP ----
    pool_mlp_kernel<<<NG, 256, 0, stream>>>(A, batch, fc1w, fc1b, fc2w, fc2b,
                                            (float*)d_out, N);
}